// Round 1
// baseline (413.275 us; speedup 1.0000x reference)
//
#include <hip/hip_runtime.h>

// qg_flux: 2-cycle multigrid Helmholtz solve + Arakawa/laplacian flux epilogue.
// All f32. BATCH=16, levels n = {513,257,129,65,33,17,9,5}.
// ws usage: psis (22.5MB) + qs (22.5MB) + tmp (16.8MB) = ~61.8MB f32.

#define NLEV 8
#define NB 16

__global__ void scale_copy_k(const float* __restrict__ in, float* __restrict__ out,
                             int ntot, float s) {
  int i = blockIdx.x * 256 + threadIdx.x;
  if (i < ntot) out[i] = in[i] * s;
}

// out = _pad1( c * (up + down + left + right - q) )
__global__ void relax_k(const float* __restrict__ psi, const float* __restrict__ q,
                        float* __restrict__ out, int n, float c) {
  int j = blockIdx.x * 64 + threadIdx.x;
  int i = blockIdx.y * 4 + threadIdx.y;
  if (i >= n || j >= n) return;
  size_t base = (size_t)blockIdx.z * n * n;
  float v = 0.f;
  if (i > 0 && i < n - 1 && j > 0 && j < n - 1) {
    const float* p = psi + base;
    v = c * (p[(size_t)(i - 1) * n + j] + p[(size_t)(i + 1) * n + j] +
             p[(size_t)i * n + (j - 1)] + p[(size_t)i * n + (j + 1)] -
             q[base + (size_t)i * n + j]);
  }
  out[base + (size_t)i * n + j] = v;
}

// relax applied to an all-zero psi: out = _pad1( -c * q )
__global__ void relax_zero_k(const float* __restrict__ q, float* __restrict__ out,
                             int n, float c) {
  int j = blockIdx.x * 64 + threadIdx.x;
  int i = blockIdx.y * 4 + threadIdx.y;
  if (i >= n || j >= n) return;
  size_t base = (size_t)blockIdx.z * n * n;
  float v = 0.f;
  if (i > 0 && i < n - 1 && j > 0 && j < n - 1)
    v = -c * q[base + (size_t)i * n + j];
  out[base + (size_t)i * n + j] = v;
}

// qC[ic,jc] = 4*(d*psiF[2ic,2jc] - N - S - W - E + qF[2ic,2jc]) on coarse interior, 0 on boundary
__global__ void rescale_k(const float* __restrict__ psiF, const float* __restrict__ qF,
                          float* __restrict__ qC, int nf, int nc, float d) {
  int jc = blockIdx.x * 64 + threadIdx.x;
  int ic = blockIdx.y * 4 + threadIdx.y;
  if (ic >= nc || jc >= nc) return;
  size_t cb = (size_t)blockIdx.z * nc * nc, fb = (size_t)blockIdx.z * nf * nf;
  float v = 0.f;
  if (ic >= 1 && ic < nc - 1 && jc >= 1 && jc < nc - 1) {
    int fi = 2 * ic, fj = 2 * jc;
    const float* p = psiF + fb;
    v = 4.f * (d * p[(size_t)fi * nf + fj]
               - p[(size_t)(fi - 1) * nf + fj] - p[(size_t)(fi + 1) * nf + fj]
               - p[(size_t)fi * nf + fj - 1] - p[(size_t)fi * nf + fj + 1]
               + qF[fb + (size_t)fi * nf + fj]);
  }
  qC[cb + (size_t)ic * nc + jc] = v;
}

// pf += bilinear_up(pc); nf = 2*nc-1 so weights are exactly {0, 0.5}
__global__ void prolong_add_k(const float* __restrict__ pc, float* __restrict__ pf,
                              int nc, int nf) {
  int j = blockIdx.x * 64 + threadIdx.x;
  int i = blockIdx.y * 4 + threadIdx.y;
  if (i >= nf || j >= nf) return;
  size_t cb = (size_t)blockIdx.z * nc * nc, fb = (size_t)blockIdx.z * nf * nf;
  const float* c = pc + cb;
  int i0 = i >> 1, j0 = j >> 1;
  float a = c[(size_t)i0 * nc + j0];
  float v;
  if ((i & 1) == 0) {
    if ((j & 1) == 0) v = a;
    else              v = 0.5f * (a + c[(size_t)i0 * nc + j0 + 1]);
  } else {
    if ((j & 1) == 0) v = 0.5f * (a + c[(size_t)(i0 + 1) * nc + j0]);
    else              v = 0.25f * (a + c[(size_t)(i0 + 1) * nc + j0] +
                                   c[(size_t)i0 * nc + j0 + 1] +
                                   c[(size_t)(i0 + 1) * nc + j0 + 1]);
  }
  pf[fb + (size_t)i * nf + j] += v;
}

// Fused epilogue: PSI passthrough out + QFLUX = pad( -J - RKB*Z + RKH*Z2 - RKH2*Z4
//                 + CURLT - (0.5/DX)*(PSI_E - PSI_W) )
// Z/Z2 carry the _pad1 zero-boundary between laplacian applications.
#define TS 16
__global__ __launch_bounds__(256) void flux_k(
    const float* __restrict__ PSI, const float* __restrict__ Q,
    const float* __restrict__ CT, float* __restrict__ psi_out,
    float* __restrict__ qf_out, int n) {
  const float INV_DX2 = 262144.0f;            // 1/dx^2, exact
  const float CENTER  = 1048576.0f;           // 2/dx^2 + 2/dy^2, exact
  const float INV12   = (float)(262144.0 / 12.0);  // 1/(12*dx*dy)
  int ti = blockIdx.y * TS, tj = blockIdx.x * TS;
  size_t base = (size_t)blockIdx.z * n * n;
  __shared__ float sP[22][23];
  __shared__ float sQ[18][19];
  __shared__ float sZ[20][21];
  __shared__ float sZ2[18][19];
  int lid = threadIdx.y * TS + threadIdx.x;
  for (int t = lid; t < 22 * 22; t += 256) {
    int r = t / 22, c = t % 22;
    int gi = ti - 3 + r, gj = tj - 3 + c;
    sP[r][c] = (gi >= 0 && gi < n && gj >= 0 && gj < n) ? PSI[base + (size_t)gi * n + gj] : 0.f;
  }
  for (int t = lid; t < 18 * 18; t += 256) {
    int r = t / 18, c = t % 18;
    int gi = ti - 1 + r, gj = tj - 1 + c;
    sQ[r][c] = (gi >= 0 && gi < n && gj >= 0 && gj < n) ? Q[base + (size_t)gi * n + gj] : 0.f;
  }
  __syncthreads();
  // Z over halo-2 region; global (ti-2+r, tj-2+c); sP index shift +1
  for (int t = lid; t < 20 * 20; t += 256) {
    int r = t / 20, c = t % 20;
    int gi = ti - 2 + r, gj = tj - 2 + c;
    float v = 0.f;
    if (gi >= 1 && gi < n - 1 && gj >= 1 && gj < n - 1)
      v = (sP[r + 1][c] + sP[r + 1][c + 2] + sP[r][c + 1] + sP[r + 2][c + 1]) * INV_DX2
          - sP[r + 1][c + 1] * CENTER;
    sZ[r][c] = v;
  }
  __syncthreads();
  // Z2 over halo-1 region; global (ti-1+r, tj-1+c); sZ index shift +1
  for (int t = lid; t < 18 * 18; t += 256) {
    int r = t / 18, c = t % 18;
    int gi = ti - 1 + r, gj = tj - 1 + c;
    float v = 0.f;
    if (gi >= 1 && gi < n - 1 && gj >= 1 && gj < n - 1)
      v = (sZ[r + 1][c] + sZ[r + 1][c + 2] + sZ[r][c + 1] + sZ[r + 2][c + 1]) * INV_DX2
          - sZ[r + 1][c + 1] * CENTER;
    sZ2[r][c] = v;
  }
  __syncthreads();
  int i = ti + threadIdx.y, j = tj + threadIdx.x;
  if (i >= n || j >= n) return;
  size_t idx = base + (size_t)i * n + j;
  int pr = threadIdx.y + 3, pc = threadIdx.x + 3;
  psi_out[idx] = sP[pr][pc];
  float qv = 0.f;
  if (i >= 1 && i < n - 1 && j >= 1 && j < n - 1) {
    int r = threadIdx.y + 1, c = threadIdx.x + 1;
    float z4 = (sZ2[r][c - 1] + sZ2[r][c + 1] + sZ2[r - 1][c] + sZ2[r + 1][c]) * INV_DX2
               - sZ2[r][c] * CENTER;
    float z2v = sZ2[r][c];
    float z1v = sZ[threadIdx.y + 2][threadIdx.x + 2];
    float Amm = sP[pr - 1][pc - 1], Am0 = sP[pr - 1][pc], Amp = sP[pr - 1][pc + 1];
    float A0m = sP[pr][pc - 1],     A0p = sP[pr][pc + 1];
    float Apm = sP[pr + 1][pc - 1], Ap0 = sP[pr + 1][pc], App = sP[pr + 1][pc + 1];
    int qr = threadIdx.y + 1, qc = threadIdx.x + 1;
    float J = (A0m - Am0) * sQ[qr - 1][qc - 1]
            + (Amm + A0m - Amp - A0p) * sQ[qr - 1][qc]
            + (Am0 - A0p) * sQ[qr - 1][qc + 1]
            + (Apm + Ap0 - Amm - Am0) * sQ[qr][qc - 1]
            + (Am0 + Amp - Ap0 - App) * sQ[qr][qc + 1]
            + (Ap0 - A0m) * sQ[qr + 1][qc - 1]
            + (A0p + App - A0m - Apm) * sQ[qr + 1][qc]
            + (A0p - Ap0) * sQ[qr + 1][qc + 1];
    J *= INV12;
    float ct = CT[(size_t)i * n + j];  // CURLT is (1,M,N), broadcast over batch
    qv = -J - 1e-6f * z1v + 1e-8f * z2v - 2e-11f * z4 + ct - 256.0f * (A0p - A0m);
  }
  qf_out[idx] = qv;
}

extern "C" void kernel_launch(void* const* d_in, const int* in_sizes, int n_in,
                              void* d_out, int out_size, void* d_ws, size_t ws_size,
                              hipStream_t stream) {
  // inputs: d_in[0]=t (unused), d_in[1]=PSIGUESS f32, d_in[2]=Q f32, d_in[3]=CURLT f32
  const float* PSIG = (const float*)d_in[1];
  const float* Q    = (const float*)d_in[2];
  const float* CT   = (const float*)d_in[3];

  static const int ns[NLEV] = {513, 257, 129, 65, 33, 17, 9, 5};
  double HS[NLEV];
  for (int k = 0; k < NLEV; k++) HS[k] = 0.25 / (double)(1 << (7 - k));

  float* ws = (float*)d_ws;
  float* psi[NLEV];
  float* qv[NLEV];
  size_t off = 0;
  for (int k = 0; k < NLEV; k++) { psi[k] = ws + off; off += (size_t)NB * ns[k] * ns[k]; }
  for (int k = 0; k < NLEV; k++) { qv[k]  = ws + off; off += (size_t)NB * ns[k] * ns[k]; }
  float* tmp = ws + off;  // level-0-sized ping buffer, reused at every level

  // qs[0] = Q * h0^2
  int ntot0 = NB * ns[0] * ns[0];
  scale_copy_k<<<dim3((ntot0 + 255) / 256), dim3(256), 0, stream>>>(
      Q, qv[0], ntot0, (float)(HS[0] * HS[0]));

  for (int cyc = 0; cyc < 2; cyc++) {
    // ---- down leg ----
    for (int k = 0; k < NLEV; k++) {
      int n = ns[k];
      float c = (float)(1.0 / (4.0 + 1600.0 * HS[k] * HS[k]));
      dim3 blk(64, 4, 1), grd((n + 63) / 64, (n + 3) / 4, NB);
      if (k == 0) {
        const float* src = (cyc == 0) ? PSIG : psi[0];
        relax_k<<<grd, blk, 0, stream>>>(src, qv[0], tmp, n, c);
      } else {
        // psis[k] = 0 then relax  ==  -c*q on interior
        relax_zero_k<<<grd, blk, 0, stream>>>(qv[k], tmp, n, c);
      }
      relax_k<<<grd, blk, 0, stream>>>(tmp, qv[k], psi[k], n, c);
      if (k < NLEV - 1) {
        int nc = ns[k + 1];
        float d = (float)(4.0 + 1600.0 * HS[k] * HS[k]);
        dim3 grd2((nc + 63) / 64, (nc + 3) / 4, NB);
        rescale_k<<<grd2, blk, 0, stream>>>(psi[k], qv[k], qv[k + 1], n, nc, d);
      }
    }
    // ---- up leg (reference's exact, unusual schedule) ----
    for (int kk = 0; kk < NLEV; kk++) {
      int lvl = NLEV - 1 - kk;
      int n = ns[lvl];
      float c = (float)(1.0 / (4.0 + 1600.0 * HS[lvl] * HS[lvl]));
      dim3 blk(64, 4, 1), grd((n + 63) / 64, (n + 3) / 4, NB);
      relax_k<<<grd, blk, 0, stream>>>(psi[lvl], qv[lvl], tmp, n, c);
      relax_k<<<grd, blk, 0, stream>>>(tmp, qv[lvl], psi[lvl], n, c);
      if (kk > 0) {
        int nf = ns[kk - 1], ncr = ns[kk];
        dim3 grdp((nf + 63) / 64, (nf + 3) / 4, NB);
        prolong_add_k<<<grdp, blk, 0, stream>>>(psi[kk], psi[kk - 1], ncr, nf);
      }
    }
  }

  // outputs: PSI then QFLUX, concatenated flat, f32
  float* psi_out = (float*)d_out;
  float* qf_out  = psi_out + (size_t)NB * ns[0] * ns[0];
  dim3 fb(16, 16, 1), fg((ns[0] + 15) / 16, (ns[0] + 15) / 16, NB);
  flux_k<<<fg, fb, 0, stream>>>(psi[0], Q, CT, psi_out, qf_out, ns[0]);
}

// Round 2
// 170.393 us; speedup vs baseline: 2.4254x; 2.4254x over previous
//
#include <hip/hip_runtime.h>

// qg_flux, round 2: dead-code-eliminated multigrid.
// Only levels 0 and 1 are live (everything deeper never feeds psis[0]).
// Per cycle: psi0 = relax^2(psi0_prev, q0); q1 = rescale(psi0, q0);
//            psi1 = relax(relax(0,q1),q1); psi0 = relax^2(psi0 + up(psi1), q0).
// q0 = Q*h0^2 is folded into every consumer (never materialized).

#define N0 513
#define N1 257
#define NB 16

__device__ __forceinline__ float c0f() { return (float)(1.0 / (4.0 + 1600.0 * (0.001953125 * 0.001953125))); }
__device__ __forceinline__ float d0f() { return (float)(4.0 + 1600.0 * (0.001953125 * 0.001953125)); }
__device__ __forceinline__ float c1f() { return (float)(1.0 / (4.0 + 1600.0 * (0.00390625 * 0.00390625))); }
#define H0SQ 3.814697265625e-06f

// Fused two Jacobi sweeps at 513^2; optionally adds bilinear prolongation of
// the 257^2 coarse correction to the input field first.
template<bool ADD_UP>
__global__ __launch_bounds__(256) void drelax_k(
    const float* __restrict__ psi, const float* __restrict__ Qg,
    const float* __restrict__ pc, float* __restrict__ out) {
  const int n = N0;
  const float C0 = c0f();
  int ti = blockIdx.y * 32, tj = blockIdx.x * 32;
  size_t base = (size_t)blockIdx.z * (n * n);
  const float* P = psi + base;
  const float* Q = Qg + base;
  const float* C = pc + (size_t)blockIdx.z * (N1 * N1);
  __shared__ float sP[36][37];
  __shared__ float sQ[34][35];
  __shared__ float sT[34][35];
  int lid = threadIdx.y * 32 + threadIdx.x;
  for (int t = lid; t < 36 * 36; t += 256) {
    int r = t / 36, c = t % 36;
    int gi = ti - 2 + r, gj = tj - 2 + c;
    float v = 0.f;
    if (gi >= 0 && gi < n && gj >= 0 && gj < n) {
      v = P[(size_t)gi * n + gj];
      if (ADD_UP) {
        int i0 = gi >> 1, j0 = gj >> 1;
        float a = C[i0 * N1 + j0];
        float up;
        if ((gi & 1) == 0) {
          if ((gj & 1) == 0) up = a;
          else               up = 0.5f * (a + C[i0 * N1 + j0 + 1]);
        } else {
          if ((gj & 1) == 0) up = 0.5f * (a + C[(i0 + 1) * N1 + j0]);
          else               up = 0.25f * (a + C[(i0 + 1) * N1 + j0] +
                                           C[i0 * N1 + j0 + 1] + C[(i0 + 1) * N1 + j0 + 1]);
        }
        v += up;
      }
    }
    sP[r][c] = v;
  }
  for (int t = lid; t < 34 * 34; t += 256) {
    int r = t / 34, c = t % 34;
    int gi = ti - 1 + r, gj = tj - 1 + c;
    sQ[r][c] = (gi >= 0 && gi < n && gj >= 0 && gj < n) ? Q[(size_t)gi * n + gj] * H0SQ : 0.f;
  }
  __syncthreads();
  // sweep 1 over halo-1 region
  for (int t = lid; t < 34 * 34; t += 256) {
    int r = t / 34, c = t % 34;
    int gi = ti - 1 + r, gj = tj - 1 + c;
    float v = 0.f;
    if (gi >= 1 && gi < n - 1 && gj >= 1 && gj < n - 1)
      v = C0 * (sP[r][c + 1] + sP[r + 2][c + 1] + sP[r + 1][c] + sP[r + 1][c + 2] - sQ[r][c]);
    sT[r][c] = v;
  }
  __syncthreads();
  // sweep 2, 4 output rows per thread
  #pragma unroll
  for (int s = 0; s < 4; s++) {
    int yy = threadIdx.y + 8 * s;
    int i = ti + yy, j = tj + threadIdx.x;
    if (i < n && j < n) {
      float v = 0.f;
      if (i >= 1 && i < n - 1 && j >= 1 && j < n - 1) {
        int r = yy + 1, c = threadIdx.x + 1;
        v = C0 * (sT[r - 1][c] + sT[r + 1][c] + sT[r][c - 1] + sT[r][c + 1] - sQ[r][c]);
      }
      out[base + (size_t)i * n + j] = v;
    }
  }
}

// q1 = rescale(psi0, Q*h0^2): coarse 257^2 from fine 513^2
__global__ void rescale2_k(const float* __restrict__ psi0, const float* __restrict__ Qg,
                           float* __restrict__ q1) {
  int jc = blockIdx.x * 64 + threadIdx.x;
  int ic = blockIdx.y * 4 + threadIdx.y;
  if (ic >= N1 || jc >= N1) return;
  size_t cb = (size_t)blockIdx.z * (N1 * N1), fb = (size_t)blockIdx.z * (N0 * N0);
  float v = 0.f;
  if (ic >= 1 && ic < N1 - 1 && jc >= 1 && jc < N1 - 1) {
    int fi = 2 * ic, fj = 2 * jc;
    const float* p = psi0 + fb;
    v = 4.f * (d0f() * p[(size_t)fi * N0 + fj]
               - p[(size_t)(fi - 1) * N0 + fj] - p[(size_t)(fi + 1) * N0 + fj]
               - p[(size_t)fi * N0 + fj - 1] - p[(size_t)fi * N0 + fj + 1]
               + Qg[fb + (size_t)fi * N0 + fj] * H0SQ);
  }
  q1[cb + (size_t)ic * N1 + jc] = v;
}

// psi1 = relax(relax(0, q1), q1) at 257^2. q1 boundary is stored 0, so the
// intermediate t = -c1*q1 holds everywhere it is read.
__global__ void coarse_drelax_k(const float* __restrict__ q1, float* __restrict__ p1) {
  const float C1 = c1f();
  int j = blockIdx.x * 64 + threadIdx.x;
  int i = blockIdx.y * 4 + threadIdx.y;
  if (i >= N1 || j >= N1) return;
  size_t b = (size_t)blockIdx.z * (N1 * N1);
  float v = 0.f;
  if (i >= 1 && i < N1 - 1 && j >= 1 && j < N1 - 1) {
    const float* q = q1 + b;
    float tN = -C1 * q[(size_t)(i - 1) * N1 + j];
    float tS = -C1 * q[(size_t)(i + 1) * N1 + j];
    float tW = -C1 * q[(size_t)i * N1 + j - 1];
    float tE = -C1 * q[(size_t)i * N1 + j + 1];
    v = C1 * (tN + tS + tW + tE - q[(size_t)i * N1 + j]);
  }
  p1[b + (size_t)i * N1 + j] = v;
}

// Fused epilogue (unchanged from round 1): J, Z, Z2, Z4, QFLUX + PSI copy-out.
#define TS 16
__global__ __launch_bounds__(256) void flux_k(
    const float* __restrict__ PSI, const float* __restrict__ Q,
    const float* __restrict__ CT, float* __restrict__ psi_out,
    float* __restrict__ qf_out, int n) {
  const float INV_DX2 = 262144.0f;
  const float CENTER  = 1048576.0f;
  const float INV12   = (float)(262144.0 / 12.0);
  int ti = blockIdx.y * TS, tj = blockIdx.x * TS;
  size_t base = (size_t)blockIdx.z * n * n;
  __shared__ float sP[22][23];
  __shared__ float sQ[18][19];
  __shared__ float sZ[20][21];
  __shared__ float sZ2[18][19];
  int lid = threadIdx.y * TS + threadIdx.x;
  for (int t = lid; t < 22 * 22; t += 256) {
    int r = t / 22, c = t % 22;
    int gi = ti - 3 + r, gj = tj - 3 + c;
    sP[r][c] = (gi >= 0 && gi < n && gj >= 0 && gj < n) ? PSI[base + (size_t)gi * n + gj] : 0.f;
  }
  for (int t = lid; t < 18 * 18; t += 256) {
    int r = t / 18, c = t % 18;
    int gi = ti - 1 + r, gj = tj - 1 + c;
    sQ[r][c] = (gi >= 0 && gi < n && gj >= 0 && gj < n) ? Q[base + (size_t)gi * n + gj] : 0.f;
  }
  __syncthreads();
  for (int t = lid; t < 20 * 20; t += 256) {
    int r = t / 20, c = t % 20;
    int gi = ti - 2 + r, gj = tj - 2 + c;
    float v = 0.f;
    if (gi >= 1 && gi < n - 1 && gj >= 1 && gj < n - 1)
      v = (sP[r + 1][c] + sP[r + 1][c + 2] + sP[r][c + 1] + sP[r + 2][c + 1]) * INV_DX2
          - sP[r + 1][c + 1] * CENTER;
    sZ[r][c] = v;
  }
  __syncthreads();
  for (int t = lid; t < 18 * 18; t += 256) {
    int r = t / 18, c = t % 18;
    int gi = ti - 1 + r, gj = tj - 1 + c;
    float v = 0.f;
    if (gi >= 1 && gi < n - 1 && gj >= 1 && gj < n - 1)
      v = (sZ[r + 1][c] + sZ[r + 1][c + 2] + sZ[r][c + 1] + sZ[r + 2][c + 1]) * INV_DX2
          - sZ[r + 1][c + 1] * CENTER;
    sZ2[r][c] = v;
  }
  __syncthreads();
  int i = ti + threadIdx.y, j = tj + threadIdx.x;
  if (i >= n || j >= n) return;
  size_t idx = base + (size_t)i * n + j;
  int pr = threadIdx.y + 3, pc = threadIdx.x + 3;
  psi_out[idx] = sP[pr][pc];
  float qv = 0.f;
  if (i >= 1 && i < n - 1 && j >= 1 && j < n - 1) {
    int r = threadIdx.y + 1, c = threadIdx.x + 1;
    float z4 = (sZ2[r][c - 1] + sZ2[r][c + 1] + sZ2[r - 1][c] + sZ2[r + 1][c]) * INV_DX2
               - sZ2[r][c] * CENTER;
    float z2v = sZ2[r][c];
    float z1v = sZ[threadIdx.y + 2][threadIdx.x + 2];
    float Amm = sP[pr - 1][pc - 1], Am0 = sP[pr - 1][pc], Amp = sP[pr - 1][pc + 1];
    float A0m = sP[pr][pc - 1],     A0p = sP[pr][pc + 1];
    float Apm = sP[pr + 1][pc - 1], Ap0 = sP[pr + 1][pc], App = sP[pr + 1][pc + 1];
    int qr = threadIdx.y + 1, qc = threadIdx.x + 1;
    float J = (A0m - Am0) * sQ[qr - 1][qc - 1]
            + (Amm + A0m - Amp - A0p) * sQ[qr - 1][qc]
            + (Am0 - A0p) * sQ[qr - 1][qc + 1]
            + (Apm + Ap0 - Amm - Am0) * sQ[qr][qc - 1]
            + (Am0 + Amp - Ap0 - App) * sQ[qr][qc + 1]
            + (Ap0 - A0m) * sQ[qr + 1][qc - 1]
            + (A0p + App - A0m - Apm) * sQ[qr + 1][qc]
            + (A0p - Ap0) * sQ[qr + 1][qc + 1];
    J *= INV12;
    float ct = CT[(size_t)i * n + j];
    qv = -J - 1e-6f * z1v + 1e-8f * z2v - 2e-11f * z4 + ct - 256.0f * (A0p - A0m);
  }
  qf_out[idx] = qv;
}

extern "C" void kernel_launch(void* const* d_in, const int* in_sizes, int n_in,
                              void* d_out, int out_size, void* d_ws, size_t ws_size,
                              hipStream_t stream) {
  const float* PSIG = (const float*)d_in[1];
  const float* Q    = (const float*)d_in[2];
  const float* CT   = (const float*)d_in[3];

  float* ws = (float*)d_ws;
  size_t f0 = (size_t)NB * N0 * N0;
  size_t f1 = (size_t)NB * N1 * N1;
  float* pA = ws;
  float* pB = pA + f0;
  float* q1 = pB + f0;
  float* p1 = q1 + f1;

  dim3 rb(32, 8, 1), rg((N0 + 31) / 32, (N0 + 31) / 32, NB);
  dim3 cb(64, 4, 1), cg((N1 + 63) / 64, (N1 + 3) / 4, NB);

  // cycle 1
  drelax_k<false><<<rg, rb, 0, stream>>>(PSIG, Q, p1, pA);
  rescale2_k<<<cg, cb, 0, stream>>>(pA, Q, q1);
  coarse_drelax_k<<<cg, cb, 0, stream>>>(q1, p1);
  drelax_k<true><<<rg, rb, 0, stream>>>(pA, Q, p1, pB);
  // cycle 2
  drelax_k<false><<<rg, rb, 0, stream>>>(pB, Q, p1, pA);
  rescale2_k<<<cg, cb, 0, stream>>>(pA, Q, q1);
  coarse_drelax_k<<<cg, cb, 0, stream>>>(q1, p1);
  drelax_k<true><<<rg, rb, 0, stream>>>(pA, Q, p1, pB);

  // outputs: PSI then QFLUX, f32, concatenated
  float* psi_out = (float*)d_out;
  float* qf_out  = psi_out + f0;
  dim3 fb(16, 16, 1), fg((N0 + 15) / 16, (N0 + 15) / 16, NB);
  flux_k<<<fg, fb, 0, stream>>>(pB, Q, CT, psi_out, qf_out, N0);
}

// Round 3
// 132.303 us; speedup vs baseline: 3.1237x; 1.2879x over previous
//
#include <hip/hip_runtime.h>

// qg_flux, round 3: 4 dispatches.
//   drelaxR: psi0 = relax^2(in, q0) AND q1 = rescale(psi0, q0)   (513^2 + 257^2 out)
//   drelaxU: psi0' = relax^2(psi0 + up(p1), q0), p1 recomputed from q1 in-LDS
//   drelaxR again (cycle 2)
//   mega:    drelaxU + full flux epilogue (Z,Z2,Z4,J,QFLUX) fused, writes outputs
// q0 = Q*h0^2 folded everywhere; levels >=2 are dead code (proven rounds 1-2).

#define N0 513
#define N1 257
#define NB 16

#define C0F ((float)(1.0 / 4.006103515625))
#define D0F 4.006103515625f
#define C1F ((float)(1.0 / 4.0244140625))
#define H0SQ 3.814697265625e-06f
#define INV_DX2 262144.0f
#define CENTER  1048576.0f
#define INV12   ((float)(262144.0 / 12.0))

// down-leg: two Jacobi sweeps + fused rescale -> q1
__global__ __launch_bounds__(256) void drelaxR_k(
    const float* __restrict__ psi, const float* __restrict__ Qg,
    float* __restrict__ out, float* __restrict__ q1) {
  const int n = N0;
  int ti = blockIdx.y * 32, tj = blockIdx.x * 32;
  size_t base = (size_t)blockIdx.z * (n * n);
  const float* P = psi + base;
  const float* Q = Qg + base;
  __shared__ float sIn[38][39];   // org ti-3
  __shared__ float sQ[36][37];    // org ti-2, scaled by H0SQ
  __shared__ float sT[36][37];    // org ti-2
  __shared__ float sP[34][35];    // org ti-1
  int lid = threadIdx.y * 32 + threadIdx.x;
  for (int t = lid; t < 38 * 38; t += 256) {
    int r = t / 38, c = t - r * 38;
    int gi = ti - 3 + r, gj = tj - 3 + c;
    sIn[r][c] = (gi >= 0 && gi < n && gj >= 0 && gj < n) ? P[(size_t)gi * n + gj] : 0.f;
  }
  for (int t = lid; t < 36 * 36; t += 256) {
    int r = t / 36, c = t - r * 36;
    int gi = ti - 2 + r, gj = tj - 2 + c;
    sQ[r][c] = (gi >= 0 && gi < n && gj >= 0 && gj < n) ? Q[(size_t)gi * n + gj] * H0SQ : 0.f;
  }
  __syncthreads();
  for (int t = lid; t < 36 * 36; t += 256) {
    int r = t / 36, c = t - r * 36;
    int gi = ti - 2 + r, gj = tj - 2 + c;
    float v = 0.f;
    if (gi >= 1 && gi < n - 1 && gj >= 1 && gj < n - 1)
      v = C0F * (sIn[r][c + 1] + sIn[r + 2][c + 1] + sIn[r + 1][c] + sIn[r + 1][c + 2] - sQ[r][c]);
    sT[r][c] = v;
  }
  __syncthreads();
  for (int t = lid; t < 34 * 34; t += 256) {
    int r = t / 34, c = t - r * 34;
    int gi = ti - 1 + r, gj = tj - 1 + c;
    float v = 0.f;
    if (gi >= 1 && gi < n - 1 && gj >= 1 && gj < n - 1)
      v = C0F * (sT[r][c + 1] + sT[r + 2][c + 1] + sT[r + 1][c] + sT[r + 1][c + 2] - sQ[r + 1][c + 1]);
    sP[r][c] = v;
  }
  __syncthreads();
  #pragma unroll
  for (int s = 0; s < 4; s++) {
    int yy = threadIdx.y + 8 * s;
    int i = ti + yy, j = tj + threadIdx.x;
    if (i < n && j < n)
      out[base + (size_t)i * n + j] = sP[yy + 1][threadIdx.x + 1];
  }
  // fused rescale: 16x16 coarse patch per block
  {
    int cy = lid >> 4, cx = lid & 15;
    int ic = 16 * blockIdx.y + cy, jc = 16 * blockIdx.x + cx;
    if (ic < N1 && jc < N1) {
      float v = 0.f;
      if (ic >= 1 && ic < N1 - 1 && jc >= 1 && jc < N1 - 1) {
        int r = 2 * cy + 1, c = 2 * cx + 1;  // sP-local of (2ic,2jc)
        v = 4.f * (D0F * sP[r][c] - sP[r - 1][c] - sP[r + 1][c] - sP[r][c - 1] - sP[r][c + 1]
                   + sQ[r + 1][c + 1]);
      }
      q1[(size_t)blockIdx.z * (N1 * N1) + (size_t)ic * N1 + jc] = v;
    }
  }
}

// up-leg: p1 = relax(relax(0,q1),q1) recomputed per-block, prolong-add, two sweeps
__global__ __launch_bounds__(256) void drelaxU_k(
    const float* __restrict__ psi, const float* __restrict__ Qg,
    const float* __restrict__ q1g, float* __restrict__ out) {
  const int n = N0;
  int ti = blockIdx.y * 32, tj = blockIdx.x * 32;
  int c0i = 16 * (int)blockIdx.y - 1, c0j = 16 * (int)blockIdx.x - 1;  // sp1 origin
  size_t base = (size_t)blockIdx.z * (n * n);
  const float* P = psi + base;
  const float* Q = Qg + base;
  const float* q1 = q1g + (size_t)blockIdx.z * (N1 * N1);
  __shared__ float sIn[36][37];   // org ti-2
  __shared__ float sQ[34][35];    // org ti-1, scaled
  __shared__ float sT[34][35];    // org ti-1
  __shared__ float sq1[21][22];   // coarse org c0-1
  __shared__ float sp1[19][20];   // coarse org c0
  int lid = threadIdx.y * 32 + threadIdx.x;
  for (int t = lid; t < 21 * 21; t += 256) {
    int r = t / 21, c = t - r * 21;
    int ci = c0i - 1 + r, cj = c0j - 1 + c;
    sq1[r][c] = (ci >= 0 && ci < N1 && cj >= 0 && cj < N1) ? q1[(size_t)ci * N1 + cj] : 0.f;
  }
  for (int t = lid; t < 34 * 34; t += 256) {
    int r = t / 34, c = t - r * 34;
    int gi = ti - 1 + r, gj = tj - 1 + c;
    sQ[r][c] = (gi >= 0 && gi < n && gj >= 0 && gj < n) ? Q[(size_t)gi * n + gj] * H0SQ : 0.f;
  }
  __syncthreads();
  for (int t = lid; t < 19 * 19; t += 256) {
    int r = t / 19, c = t - r * 19;
    int ci = c0i + r, cj = c0j + c;
    float v = 0.f;
    if (ci >= 1 && ci < N1 - 1 && cj >= 1 && cj < N1 - 1)
      v = C1F * (-C1F * (sq1[r][c + 1] + sq1[r + 2][c + 1] + sq1[r + 1][c] + sq1[r + 1][c + 2])
                 - sq1[r + 1][c + 1]);
    sp1[r][c] = v;
  }
  __syncthreads();
  for (int t = lid; t < 36 * 36; t += 256) {
    int r = t / 36, c = t - r * 36;
    int gi = ti - 2 + r, gj = tj - 2 + c;
    float v = 0.f;
    if (gi >= 0 && gi < n && gj >= 0 && gj < n) {
      v = P[(size_t)gi * n + gj];
      int r1 = (gi >> 1) - c0i, c1 = (gj >> 1) - c0j;
      float a = sp1[r1][c1], up;
      if ((gi & 1) == 0) {
        up = ((gj & 1) == 0) ? a : 0.5f * (a + sp1[r1][c1 + 1]);
      } else {
        if ((gj & 1) == 0) up = 0.5f * (a + sp1[r1 + 1][c1]);
        else up = 0.25f * (a + sp1[r1 + 1][c1] + sp1[r1][c1 + 1] + sp1[r1 + 1][c1 + 1]);
      }
      v += up;
    }
    sIn[r][c] = v;
  }
  __syncthreads();
  for (int t = lid; t < 34 * 34; t += 256) {
    int r = t / 34, c = t - r * 34;
    int gi = ti - 1 + r, gj = tj - 1 + c;
    float v = 0.f;
    if (gi >= 1 && gi < n - 1 && gj >= 1 && gj < n - 1)
      v = C0F * (sIn[r][c + 1] + sIn[r + 2][c + 1] + sIn[r + 1][c] + sIn[r + 1][c + 2] - sQ[r][c]);
    sT[r][c] = v;
  }
  __syncthreads();
  #pragma unroll
  for (int s = 0; s < 4; s++) {
    int yy = threadIdx.y + 8 * s;
    int i = ti + yy, j = tj + threadIdx.x;
    if (i < n && j < n) {
      float v = 0.f;
      if (i >= 1 && i < n - 1 && j >= 1 && j < n - 1) {
        int r = yy + 1, c = threadIdx.x + 1;
        v = C0F * (sT[r - 1][c] + sT[r + 1][c] + sT[r][c - 1] + sT[r][c + 1] - sQ[r][c]);
      }
      out[base + (size_t)i * n + j] = v;
    }
  }
}

// final up-leg drelax + full flux epilogue, fused. LDS buffers aliased by stage.
__global__ __launch_bounds__(256) void mega_k(
    const float* __restrict__ psi, const float* __restrict__ Qg,
    const float* __restrict__ q1g, const float* __restrict__ CT,
    float* __restrict__ psi_out, float* __restrict__ qf_out) {
  const int n = N0;
  int ti = blockIdx.y * 32, tj = blockIdx.x * 32;
  int c0i = 16 * (int)blockIdx.y - 3, c0j = 16 * (int)blockIdx.x - 3;  // sp1 origin
  size_t base = (size_t)blockIdx.z * (n * n);
  const float* P = psi + base;
  const float* Q = Qg + base;
  const float* q1 = q1g + (size_t)blockIdx.z * (N1 * N1);
  __shared__ float bufA[42 * 43];  // sIn (42x43, org ti-5) -> sZ (36x37, org ti-2)
  __shared__ float bufB[40 * 41];  // raw Q (40x41, org ti-4)
  __shared__ float bufC[40 * 41];  // sT (40x41, org ti-4) -> sZ2 (34x35, org ti-1)
  __shared__ float bufD[38 * 39];  // sq1(25x26)+sp1(23x24) -> sP (38x39, org ti-3)
  float* sq1 = bufD;               // [25][26], coarse org c0-1
  float* sp1 = bufD + 25 * 26;     // [23][24], coarse org c0
  int lid = threadIdx.y * 32 + threadIdx.x;
  for (int t = lid; t < 25 * 25; t += 256) {
    int r = t / 25, c = t - r * 25;
    int ci = c0i - 1 + r, cj = c0j - 1 + c;
    sq1[r * 26 + c] = (ci >= 0 && ci < N1 && cj >= 0 && cj < N1) ? q1[(size_t)ci * N1 + cj] : 0.f;
  }
  for (int t = lid; t < 40 * 40; t += 256) {
    int r = t / 40, c = t - r * 40;
    int gi = ti - 4 + r, gj = tj - 4 + c;
    bufB[r * 41 + c] = (gi >= 0 && gi < n && gj >= 0 && gj < n) ? Q[(size_t)gi * n + gj] : 0.f;
  }
  __syncthreads();
  for (int t = lid; t < 23 * 23; t += 256) {   // p1
    int r = t / 23, c = t - r * 23;
    int ci = c0i + r, cj = c0j + c;
    float v = 0.f;
    if (ci >= 1 && ci < N1 - 1 && cj >= 1 && cj < N1 - 1)
      v = C1F * (-C1F * (sq1[r * 26 + c + 1] + sq1[(r + 2) * 26 + c + 1] +
                         sq1[(r + 1) * 26 + c] + sq1[(r + 1) * 26 + c + 2])
                 - sq1[(r + 1) * 26 + c + 1]);
    sp1[r * 24 + c] = v;
  }
  __syncthreads();
  for (int t = lid; t < 42 * 42; t += 256) {   // u = psi + up(p1)
    int r = t / 42, c = t - r * 42;
    int gi = ti - 5 + r, gj = tj - 5 + c;
    float v = 0.f;
    if (gi >= 0 && gi < n && gj >= 0 && gj < n) {
      v = P[(size_t)gi * n + gj];
      int r1 = (gi >> 1) - c0i, c1 = (gj >> 1) - c0j;
      float a = sp1[r1 * 24 + c1], up;
      if ((gi & 1) == 0) {
        up = ((gj & 1) == 0) ? a : 0.5f * (a + sp1[r1 * 24 + c1 + 1]);
      } else {
        if ((gj & 1) == 0) up = 0.5f * (a + sp1[(r1 + 1) * 24 + c1]);
        else up = 0.25f * (a + sp1[(r1 + 1) * 24 + c1] + sp1[r1 * 24 + c1 + 1] +
                           sp1[(r1 + 1) * 24 + c1 + 1]);
      }
      v += up;
    }
    bufA[r * 43 + c] = v;
  }
  __syncthreads();
  for (int t = lid; t < 40 * 40; t += 256) {   // sweep1 -> bufC
    int r = t / 40, c = t - r * 40;
    int gi = ti - 4 + r, gj = tj - 4 + c;
    float v = 0.f;
    if (gi >= 1 && gi < n - 1 && gj >= 1 && gj < n - 1)
      v = C0F * (bufA[r * 43 + c + 1] + bufA[(r + 2) * 43 + c + 1] +
                 bufA[(r + 1) * 43 + c] + bufA[(r + 1) * 43 + c + 2]
                 - bufB[r * 41 + c] * H0SQ);
    bufC[r * 41 + c] = v;
  }
  __syncthreads();
  for (int t = lid; t < 38 * 38; t += 256) {   // sweep2 -> bufD (sP)
    int r = t / 38, c = t - r * 38;
    int gi = ti - 3 + r, gj = tj - 3 + c;
    float v = 0.f;
    if (gi >= 1 && gi < n - 1 && gj >= 1 && gj < n - 1)
      v = C0F * (bufC[r * 41 + c + 1] + bufC[(r + 2) * 41 + c + 1] +
                 bufC[(r + 1) * 41 + c] + bufC[(r + 1) * 41 + c + 2]
                 - bufB[(r + 1) * 41 + c + 1] * H0SQ);
    bufD[r * 39 + c] = v;
  }
  __syncthreads();
  for (int t = lid; t < 36 * 36; t += 256) {   // Z -> bufA
    int r = t / 36, c = t - r * 36;
    int gi = ti - 2 + r, gj = tj - 2 + c;
    float v = 0.f;
    if (gi >= 1 && gi < n - 1 && gj >= 1 && gj < n - 1)
      v = (bufD[r * 39 + c + 1] + bufD[(r + 2) * 39 + c + 1] +
           bufD[(r + 1) * 39 + c] + bufD[(r + 1) * 39 + c + 2]) * INV_DX2
          - bufD[(r + 1) * 39 + c + 1] * CENTER;
    bufA[r * 37 + c] = v;
  }
  __syncthreads();
  for (int t = lid; t < 34 * 34; t += 256) {   // Z2 -> bufC
    int r = t / 34, c = t - r * 34;
    int gi = ti - 1 + r, gj = tj - 1 + c;
    float v = 0.f;
    if (gi >= 1 && gi < n - 1 && gj >= 1 && gj < n - 1)
      v = (bufA[r * 37 + c + 1] + bufA[(r + 2) * 37 + c + 1] +
           bufA[(r + 1) * 37 + c] + bufA[(r + 1) * 37 + c + 2]) * INV_DX2
          - bufA[(r + 1) * 37 + c + 1] * CENTER;
    bufC[r * 35 + c] = v;
  }
  __syncthreads();
  #pragma unroll
  for (int s = 0; s < 4; s++) {
    int yy = threadIdx.y + 8 * s;
    int i = ti + yy, j = tj + threadIdx.x;
    if (i >= n || j >= n) continue;
    size_t idx = base + (size_t)i * n + j;
    int pr = yy + 3, pc = threadIdx.x + 3;     // sP org ti-3
    psi_out[idx] = bufD[pr * 39 + pc];
    float qv = 0.f;
    if (i >= 1 && i < n - 1 && j >= 1 && j < n - 1) {
      float z1v = bufA[(yy + 2) * 37 + threadIdx.x + 2];
      int r2 = yy + 1, c2 = threadIdx.x + 1;
      float z2v = bufC[r2 * 35 + c2];
      float z4 = (bufC[r2 * 35 + c2 - 1] + bufC[r2 * 35 + c2 + 1] +
                  bufC[(r2 - 1) * 35 + c2] + bufC[(r2 + 1) * 35 + c2]) * INV_DX2
                 - z2v * CENTER;
      float Amm = bufD[(pr - 1) * 39 + pc - 1], Am0 = bufD[(pr - 1) * 39 + pc],
            Amp = bufD[(pr - 1) * 39 + pc + 1];
      float A0m = bufD[pr * 39 + pc - 1], A0p = bufD[pr * 39 + pc + 1];
      float Apm = bufD[(pr + 1) * 39 + pc - 1], Ap0 = bufD[(pr + 1) * 39 + pc],
            App = bufD[(pr + 1) * 39 + pc + 1];
      int qr = yy + 4, qc = threadIdx.x + 4;   // raw Q org ti-4
      float J = (A0m - Am0) * bufB[(qr - 1) * 41 + qc - 1]
              + (Amm + A0m - Amp - A0p) * bufB[(qr - 1) * 41 + qc]
              + (Am0 - A0p) * bufB[(qr - 1) * 41 + qc + 1]
              + (Apm + Ap0 - Amm - Am0) * bufB[qr * 41 + qc - 1]
              + (Am0 + Amp - Ap0 - App) * bufB[qr * 41 + qc + 1]
              + (Ap0 - A0m) * bufB[(qr + 1) * 41 + qc - 1]
              + (A0p + App - A0m - Apm) * bufB[(qr + 1) * 41 + qc]
              + (A0p - Ap0) * bufB[(qr + 1) * 41 + qc + 1];
      J *= INV12;
      float ct = CT[(size_t)i * n + j];
      qv = -J - 1e-6f * z1v + 1e-8f * z2v - 2e-11f * z4 + ct - 256.0f * (A0p - A0m);
    }
    qf_out[idx] = qv;
  }
}

extern "C" void kernel_launch(void* const* d_in, const int* in_sizes, int n_in,
                              void* d_out, int out_size, void* d_ws, size_t ws_size,
                              hipStream_t stream) {
  const float* PSIG = (const float*)d_in[1];
  const float* Q    = (const float*)d_in[2];
  const float* CT   = (const float*)d_in[3];

  float* ws = (float*)d_ws;
  size_t f0 = (size_t)NB * N0 * N0;
  size_t f1 = (size_t)NB * N1 * N1;
  float* pA = ws;
  float* pB = pA + f0;
  float* q1 = pB + f0;
  (void)f1;

  dim3 blk(32, 8, 1), grd(17, 17, NB);

  // cycle 1
  drelaxR_k<<<grd, blk, 0, stream>>>(PSIG, Q, pA, q1);
  drelaxU_k<<<grd, blk, 0, stream>>>(pA, Q, q1, pB);
  // cycle 2
  drelaxR_k<<<grd, blk, 0, stream>>>(pB, Q, pA, q1);

  float* psi_out = (float*)d_out;
  float* qf_out  = psi_out + f0;
  mega_k<<<grd, blk, 0, stream>>>(pA, Q, q1, CT, psi_out, qf_out);
}

// Round 4
// 127.092 us; speedup vs baseline: 3.2518x; 1.0410x over previous
//
#include <hip/hip_runtime.h>

// qg_flux, round 4: same 4-dispatch structure as round 3, kernel internals
// optimized: interior/edge block template (no per-point bounds checks for the
// 68% fully-interior blocks), branchless bilinear prolongation (kills 2-way
// lane divergence), H0SQ folded into mega's Q staging (J rescaled by exact
// power-of-2 constant -> bit-identical).

#define N0 513
#define N1 257
#define NB 16

#define C0F ((float)(1.0 / 4.006103515625))
#define D0F 4.006103515625f
#define C1F ((float)(1.0 / 4.0244140625))
#define H0SQ 3.814697265625e-06f            // h0^2 = 2^-18, exact
#define INV_DX2 262144.0f
#define CENTER  1048576.0f
#define INV12S  ((float)(262144.0 / 12.0 * 262144.0))  // INV12 * 2^18

// ---------------------------------------------------------------- drelaxR ---
// down-leg: psi' = relax^2(psi, q0), plus fused rescale -> q1.
template<bool INT>
__device__ __forceinline__ void drelaxR_body(
    const float* __restrict__ P, const float* __restrict__ Q,
    float* __restrict__ outp, float* __restrict__ q1p,
    int ti, int tj, int ic0, int jc0, size_t base, size_t cbase, int lid,
    float* __restrict__ sIn, float* __restrict__ sQ,
    float* __restrict__ sT, float* __restrict__ sP) {
  const int n = N0;
  for (int t = lid; t < 38 * 38; t += 256) {
    int r = t / 38, c = t - r * 38;
    int gi = ti - 3 + r, gj = tj - 3 + c;
    float v;
    if constexpr (INT) v = P[(size_t)gi * n + gj];
    else v = (gi >= 0 && gi < n && gj >= 0 && gj < n) ? P[(size_t)gi * n + gj] : 0.f;
    sIn[r * 39 + c] = v;
  }
  for (int t = lid; t < 36 * 36; t += 256) {
    int r = t / 36, c = t - r * 36;
    int gi = ti - 2 + r, gj = tj - 2 + c;
    float v;
    if constexpr (INT) v = Q[(size_t)gi * n + gj] * H0SQ;
    else v = (gi >= 0 && gi < n && gj >= 0 && gj < n) ? Q[(size_t)gi * n + gj] * H0SQ : 0.f;
    sQ[r * 37 + c] = v;
  }
  __syncthreads();
  for (int t = lid; t < 36 * 36; t += 256) {
    int r = t / 36, c = t - r * 36;
    float v = 0.f;
    if (INT || ((ti - 2 + r) >= 1 && (ti - 2 + r) < n - 1 && (tj - 2 + c) >= 1 && (tj - 2 + c) < n - 1))
      v = C0F * (sIn[r * 39 + c + 1] + sIn[(r + 2) * 39 + c + 1] +
                 sIn[(r + 1) * 39 + c] + sIn[(r + 1) * 39 + c + 2] - sQ[r * 37 + c]);
    sT[r * 37 + c] = v;
  }
  __syncthreads();
  for (int t = lid; t < 34 * 34; t += 256) {
    int r = t / 34, c = t - r * 34;
    float v = 0.f;
    if (INT || ((ti - 1 + r) >= 1 && (ti - 1 + r) < n - 1 && (tj - 1 + c) >= 1 && (tj - 1 + c) < n - 1))
      v = C0F * (sT[r * 37 + c + 1] + sT[(r + 2) * 37 + c + 1] +
                 sT[(r + 1) * 37 + c] + sT[(r + 1) * 37 + c + 2] - sQ[(r + 1) * 37 + c + 1]);
    sP[r * 35 + c] = v;
  }
  __syncthreads();
  int tx = lid & 31, ty = lid >> 5;
  #pragma unroll
  for (int s = 0; s < 4; s++) {
    int yy = ty + 8 * s;
    int i = ti + yy, j = tj + tx;
    if (INT || (i < n && j < n))
      outp[base + (size_t)i * n + j] = sP[(yy + 1) * 35 + tx + 1];
  }
  {
    int cy = lid >> 4, cx = lid & 15;
    int ic = ic0 + cy, jc = jc0 + cx;
    if constexpr (INT) {
      int r = 2 * cy + 1, c = 2 * cx + 1;
      float v = 4.f * (D0F * sP[r * 35 + c] - sP[(r - 1) * 35 + c] - sP[(r + 1) * 35 + c]
                       - sP[r * 35 + c - 1] - sP[r * 35 + c + 1] + sQ[(r + 1) * 37 + c + 1]);
      q1p[cbase + (size_t)ic * N1 + jc] = v;
    } else {
      if (ic < N1 && jc < N1) {
        float v = 0.f;
        if (ic >= 1 && ic < N1 - 1 && jc >= 1 && jc < N1 - 1) {
          int r = 2 * cy + 1, c = 2 * cx + 1;
          v = 4.f * (D0F * sP[r * 35 + c] - sP[(r - 1) * 35 + c] - sP[(r + 1) * 35 + c]
                     - sP[r * 35 + c - 1] - sP[r * 35 + c + 1] + sQ[(r + 1) * 37 + c + 1]);
        }
        q1p[cbase + (size_t)ic * N1 + jc] = v;
      }
    }
  }
}

__global__ __launch_bounds__(256) void drelaxR_k(
    const float* __restrict__ psi, const float* __restrict__ Qg,
    float* __restrict__ out, float* __restrict__ q1) {
  __shared__ float sIn[38 * 39], sQ[36 * 37], sT[36 * 37], sP[34 * 35];
  int bx = blockIdx.x, by = blockIdx.y;
  int ti = by * 32, tj = bx * 32;
  size_t base = (size_t)blockIdx.z * (N0 * N0);
  size_t cbase = (size_t)blockIdx.z * (N1 * N1);
  int lid = threadIdx.y * 32 + threadIdx.x;
  bool inter = (bx >= 1 && bx <= 14 && by >= 1 && by <= 14);
  if (inter)
    drelaxR_body<true>(psi + base, Qg + base, out, q1, ti, tj, 16 * by, 16 * bx,
                       base, cbase, lid, sIn, sQ, sT, sP);
  else
    drelaxR_body<false>(psi + base, Qg + base, out, q1, ti, tj, 16 * by, 16 * bx,
                        base, cbase, lid, sIn, sQ, sT, sP);
}

// ---------------------------------------------------------------- drelaxU ---
// up-leg: p1 recomputed from q1 in-LDS, prolong-add (branchless), relax^2.
template<bool INT>
__device__ __forceinline__ void drelaxU_body(
    const float* __restrict__ P, const float* __restrict__ Q,
    const float* __restrict__ q1, float* __restrict__ outp,
    int ti, int tj, int c0i, int c0j, size_t base, int lid,
    float* __restrict__ sIn, float* __restrict__ sQ, float* __restrict__ sT,
    float* __restrict__ sq1, float* __restrict__ sp1) {
  const int n = N0;
  for (int t = lid; t < 21 * 21; t += 256) {
    int r = t / 21, c = t - r * 21;
    int ci = c0i - 1 + r, cj = c0j - 1 + c;
    float v;
    if constexpr (INT) v = q1[(size_t)ci * N1 + cj];
    else v = (ci >= 0 && ci < N1 && cj >= 0 && cj < N1) ? q1[(size_t)ci * N1 + cj] : 0.f;
    sq1[r * 22 + c] = v;
  }
  for (int t = lid; t < 34 * 34; t += 256) {
    int r = t / 34, c = t - r * 34;
    int gi = ti - 1 + r, gj = tj - 1 + c;
    float v;
    if constexpr (INT) v = Q[(size_t)gi * n + gj] * H0SQ;
    else v = (gi >= 0 && gi < n && gj >= 0 && gj < n) ? Q[(size_t)gi * n + gj] * H0SQ : 0.f;
    sQ[r * 35 + c] = v;
  }
  __syncthreads();
  for (int t = lid; t < 19 * 19; t += 256) {
    int r = t / 19, c = t - r * 19;
    float v = 0.f;
    if (INT || ((c0i + r) >= 1 && (c0i + r) < N1 - 1 && (c0j + c) >= 1 && (c0j + c) < N1 - 1))
      v = C1F * (-C1F * (sq1[r * 22 + c + 1] + sq1[(r + 2) * 22 + c + 1] +
                         sq1[(r + 1) * 22 + c] + sq1[(r + 1) * 22 + c + 2])
                 - sq1[(r + 1) * 22 + c + 1]);
    sp1[r * 20 + c] = v;
  }
  __syncthreads();
  for (int t = lid; t < 36 * 36; t += 256) {
    int r = t / 36, c = t - r * 36;
    int gi = ti - 2 + r, gj = tj - 2 + c;
    float v = 0.f;
    if (INT || (gi >= 0 && gi < n && gj >= 0 && gj < n)) {
      int r1 = (gi >> 1) - c0i, c1 = (gj >> 1) - c0j;
      float a = sp1[r1 * 20 + c1],       b = sp1[r1 * 20 + c1 + 1];
      float e = sp1[(r1 + 1) * 20 + c1], d = sp1[(r1 + 1) * 20 + c1 + 1];
      float wx = (gj & 1) ? 0.5f : 0.f, wy = (gi & 1) ? 0.5f : 0.f;
      float r0 = a + wx * (b - a), rr = e + wx * (d - e);
      v = P[(size_t)gi * n + gj] + (r0 + wy * (rr - r0));
    }
    sIn[r * 37 + c] = v;
  }
  __syncthreads();
  for (int t = lid; t < 34 * 34; t += 256) {
    int r = t / 34, c = t - r * 34;
    float v = 0.f;
    if (INT || ((ti - 1 + r) >= 1 && (ti - 1 + r) < n - 1 && (tj - 1 + c) >= 1 && (tj - 1 + c) < n - 1))
      v = C0F * (sIn[r * 37 + c + 1] + sIn[(r + 2) * 37 + c + 1] +
                 sIn[(r + 1) * 37 + c] + sIn[(r + 1) * 37 + c + 2] - sQ[r * 35 + c]);
    sT[r * 35 + c] = v;
  }
  __syncthreads();
  int tx = lid & 31, ty = lid >> 5;
  #pragma unroll
  for (int s = 0; s < 4; s++) {
    int yy = ty + 8 * s;
    int i = ti + yy, j = tj + tx;
    if constexpr (INT) {
      float v = C0F * (sT[yy * 35 + tx + 1] + sT[(yy + 2) * 35 + tx + 1] +
                       sT[(yy + 1) * 35 + tx] + sT[(yy + 1) * 35 + tx + 2]
                       - sQ[(yy + 1) * 35 + tx + 1]);
      outp[base + (size_t)i * n + j] = v;
    } else {
      if (i < n && j < n) {
        float v = 0.f;
        if (i >= 1 && i < n - 1 && j >= 1 && j < n - 1)
          v = C0F * (sT[yy * 35 + tx + 1] + sT[(yy + 2) * 35 + tx + 1] +
                     sT[(yy + 1) * 35 + tx] + sT[(yy + 1) * 35 + tx + 2]
                     - sQ[(yy + 1) * 35 + tx + 1]);
        outp[base + (size_t)i * n + j] = v;
      }
    }
  }
}

__global__ __launch_bounds__(256) void drelaxU_k(
    const float* __restrict__ psi, const float* __restrict__ Qg,
    const float* __restrict__ q1g, float* __restrict__ out) {
  __shared__ float sIn[36 * 37], sQ[34 * 35], sT[34 * 35], sq1[21 * 22], sp1[19 * 20];
  int bx = blockIdx.x, by = blockIdx.y;
  int ti = by * 32, tj = bx * 32;
  int c0i = 16 * by - 1, c0j = 16 * bx - 1;
  size_t base = (size_t)blockIdx.z * (N0 * N0);
  const float* q1 = q1g + (size_t)blockIdx.z * (N1 * N1);
  int lid = threadIdx.y * 32 + threadIdx.x;
  bool inter = (bx >= 1 && bx <= 14 && by >= 1 && by <= 14);
  if (inter)
    drelaxU_body<true>(psi + base, Qg + base, q1, out, ti, tj, c0i, c0j, base, lid,
                       sIn, sQ, sT, sq1, sp1);
  else
    drelaxU_body<false>(psi + base, Qg + base, q1, out, ti, tj, c0i, c0j, base, lid,
                        sIn, sQ, sT, sq1, sp1);
}

// ------------------------------------------------------------------- mega ---
// final up-leg drelax + flux epilogue. bufB holds q0 = Q*2^-18 (scaled);
// J is rescaled by INV12S = INV12*2^18 (exact po2 fold, bit-identical).
template<bool INT>
__device__ __forceinline__ void mega_body(
    const float* __restrict__ P, const float* __restrict__ Q,
    const float* __restrict__ q1, const float* __restrict__ CT,
    float* __restrict__ psi_out, float* __restrict__ qf_out,
    int ti, int tj, int c0i, int c0j, size_t base, int lid,
    float* __restrict__ bufA, float* __restrict__ bufB,
    float* __restrict__ bufC, float* __restrict__ bufD) {
  const int n = N0;
  float* sq1 = bufD;            // [25][26] coarse org c0-1
  float* sp1 = bufD + 25 * 26;  // [23][24] coarse org c0
  for (int t = lid; t < 25 * 25; t += 256) {
    int r = t / 25, c = t - r * 25;
    int ci = c0i - 1 + r, cj = c0j - 1 + c;
    float v;
    if constexpr (INT) v = q1[(size_t)ci * N1 + cj];
    else v = (ci >= 0 && ci < N1 && cj >= 0 && cj < N1) ? q1[(size_t)ci * N1 + cj] : 0.f;
    sq1[r * 26 + c] = v;
  }
  for (int t = lid; t < 40 * 40; t += 256) {
    int r = t / 40, c = t - r * 40;
    int gi = ti - 4 + r, gj = tj - 4 + c;
    float v;
    if constexpr (INT) v = Q[(size_t)gi * n + gj] * H0SQ;
    else v = (gi >= 0 && gi < n && gj >= 0 && gj < n) ? Q[(size_t)gi * n + gj] * H0SQ : 0.f;
    bufB[r * 41 + c] = v;
  }
  __syncthreads();
  for (int t = lid; t < 23 * 23; t += 256) {
    int r = t / 23, c = t - r * 23;
    float v = 0.f;
    if (INT || ((c0i + r) >= 1 && (c0i + r) < N1 - 1 && (c0j + c) >= 1 && (c0j + c) < N1 - 1))
      v = C1F * (-C1F * (sq1[r * 26 + c + 1] + sq1[(r + 2) * 26 + c + 1] +
                         sq1[(r + 1) * 26 + c] + sq1[(r + 1) * 26 + c + 2])
                 - sq1[(r + 1) * 26 + c + 1]);
    sp1[r * 24 + c] = v;
  }
  __syncthreads();
  for (int t = lid; t < 42 * 42; t += 256) {   // v = psi + up(p1)
    int r = t / 42, c = t - r * 42;
    int gi = ti - 5 + r, gj = tj - 5 + c;
    float v = 0.f;
    if (INT || (gi >= 0 && gi < n && gj >= 0 && gj < n)) {
      int r1 = (gi >> 1) - c0i, c1 = (gj >> 1) - c0j;
      float a = sp1[r1 * 24 + c1],       b = sp1[r1 * 24 + c1 + 1];
      float e = sp1[(r1 + 1) * 24 + c1], d = sp1[(r1 + 1) * 24 + c1 + 1];
      float wx = (gj & 1) ? 0.5f : 0.f, wy = (gi & 1) ? 0.5f : 0.f;
      float r0 = a + wx * (b - a), rr = e + wx * (d - e);
      v = P[(size_t)gi * n + gj] + (r0 + wy * (rr - r0));
    }
    bufA[r * 43 + c] = v;
  }
  __syncthreads();
  for (int t = lid; t < 40 * 40; t += 256) {   // sweep1
    int r = t / 40, c = t - r * 40;
    float v = 0.f;
    if (INT || ((ti - 4 + r) >= 1 && (ti - 4 + r) < n - 1 && (tj - 4 + c) >= 1 && (tj - 4 + c) < n - 1))
      v = C0F * (bufA[r * 43 + c + 1] + bufA[(r + 2) * 43 + c + 1] +
                 bufA[(r + 1) * 43 + c] + bufA[(r + 1) * 43 + c + 2] - bufB[r * 41 + c]);
    bufC[r * 41 + c] = v;
  }
  __syncthreads();
  for (int t = lid; t < 38 * 38; t += 256) {   // sweep2 -> bufD (sP)
    int r = t / 38, c = t - r * 38;
    float v = 0.f;
    if (INT || ((ti - 3 + r) >= 1 && (ti - 3 + r) < n - 1 && (tj - 3 + c) >= 1 && (tj - 3 + c) < n - 1))
      v = C0F * (bufC[r * 41 + c + 1] + bufC[(r + 2) * 41 + c + 1] +
                 bufC[(r + 1) * 41 + c] + bufC[(r + 1) * 41 + c + 2] - bufB[(r + 1) * 41 + c + 1]);
    bufD[r * 39 + c] = v;
  }
  __syncthreads();
  for (int t = lid; t < 36 * 36; t += 256) {   // Z -> bufA
    int r = t / 36, c = t - r * 36;
    float v = 0.f;
    if (INT || ((ti - 2 + r) >= 1 && (ti - 2 + r) < n - 1 && (tj - 2 + c) >= 1 && (tj - 2 + c) < n - 1))
      v = (bufD[r * 39 + c + 1] + bufD[(r + 2) * 39 + c + 1] +
           bufD[(r + 1) * 39 + c] + bufD[(r + 1) * 39 + c + 2]) * INV_DX2
          - bufD[(r + 1) * 39 + c + 1] * CENTER;
    bufA[r * 37 + c] = v;
  }
  __syncthreads();
  for (int t = lid; t < 34 * 34; t += 256) {   // Z2 -> bufC
    int r = t / 34, c = t - r * 34;
    float v = 0.f;
    if (INT || ((ti - 1 + r) >= 1 && (ti - 1 + r) < n - 1 && (tj - 1 + c) >= 1 && (tj - 1 + c) < n - 1))
      v = (bufA[r * 37 + c + 1] + bufA[(r + 2) * 37 + c + 1] +
           bufA[(r + 1) * 37 + c] + bufA[(r + 1) * 37 + c + 2]) * INV_DX2
          - bufA[(r + 1) * 37 + c + 1] * CENTER;
    bufC[r * 35 + c] = v;
  }
  __syncthreads();
  int tx = lid & 31, ty = lid >> 5;
  #pragma unroll
  for (int s = 0; s < 4; s++) {
    int yy = ty + 8 * s;
    int i = ti + yy, j = tj + tx;
    if (!INT && (i >= n || j >= n)) continue;
    size_t idx = base + (size_t)i * n + j;
    int pr = yy + 3, pc = tx + 3;
    psi_out[idx] = bufD[pr * 39 + pc];
    float qv = 0.f;
    if (INT || (i >= 1 && i < n - 1 && j >= 1 && j < n - 1)) {
      float z1v = bufA[(yy + 2) * 37 + tx + 2];
      int r2 = yy + 1, c2 = tx + 1;
      float z2v = bufC[r2 * 35 + c2];
      float z4 = (bufC[r2 * 35 + c2 - 1] + bufC[r2 * 35 + c2 + 1] +
                  bufC[(r2 - 1) * 35 + c2] + bufC[(r2 + 1) * 35 + c2]) * INV_DX2
                 - z2v * CENTER;
      float Amm = bufD[(pr - 1) * 39 + pc - 1], Am0 = bufD[(pr - 1) * 39 + pc],
            Amp = bufD[(pr - 1) * 39 + pc + 1];
      float A0m = bufD[pr * 39 + pc - 1], A0p = bufD[pr * 39 + pc + 1];
      float Apm = bufD[(pr + 1) * 39 + pc - 1], Ap0 = bufD[(pr + 1) * 39 + pc],
            App = bufD[(pr + 1) * 39 + pc + 1];
      int qr = yy + 4, qc = tx + 4;
      float J = (A0m - Am0) * bufB[(qr - 1) * 41 + qc - 1]
              + (Amm + A0m - Amp - A0p) * bufB[(qr - 1) * 41 + qc]
              + (Am0 - A0p) * bufB[(qr - 1) * 41 + qc + 1]
              + (Apm + Ap0 - Amm - Am0) * bufB[qr * 41 + qc - 1]
              + (Am0 + Amp - Ap0 - App) * bufB[qr * 41 + qc + 1]
              + (Ap0 - A0m) * bufB[(qr + 1) * 41 + qc - 1]
              + (A0p + App - A0m - Apm) * bufB[(qr + 1) * 41 + qc]
              + (A0p - Ap0) * bufB[(qr + 1) * 41 + qc + 1];
      J *= INV12S;
      float ct = CT[(size_t)i * n + j];
      qv = -J - 1e-6f * z1v + 1e-8f * z2v - 2e-11f * z4 + ct - 256.0f * (A0p - A0m);
    }
    qf_out[idx] = qv;
  }
}

__global__ __launch_bounds__(256) void mega_k(
    const float* __restrict__ psi, const float* __restrict__ Qg,
    const float* __restrict__ q1g, const float* __restrict__ CT,
    float* __restrict__ psi_out, float* __restrict__ qf_out) {
  __shared__ float bufA[42 * 43];  // v1 -> Z
  __shared__ float bufB[40 * 41];  // q0 scaled
  __shared__ float bufC[40 * 41];  // sweep1 t -> Z2
  __shared__ float bufD[38 * 39];  // coarse (sq1+sp1) -> sP
  int bx = blockIdx.x, by = blockIdx.y;
  int ti = by * 32, tj = bx * 32;
  int c0i = 16 * by - 3, c0j = 16 * bx - 3;
  size_t base = (size_t)blockIdx.z * (N0 * N0);
  const float* q1 = q1g + (size_t)blockIdx.z * (N1 * N1);
  int lid = threadIdx.y * 32 + threadIdx.x;
  bool inter = (bx >= 1 && bx <= 14 && by >= 1 && by <= 14);
  if (inter)
    mega_body<true>(psi + base, Qg + base, q1, CT, psi_out, qf_out,
                    ti, tj, c0i, c0j, base, lid, bufA, bufB, bufC, bufD);
  else
    mega_body<false>(psi + base, Qg + base, q1, CT, psi_out, qf_out,
                     ti, tj, c0i, c0j, base, lid, bufA, bufB, bufC, bufD);
}

extern "C" void kernel_launch(void* const* d_in, const int* in_sizes, int n_in,
                              void* d_out, int out_size, void* d_ws, size_t ws_size,
                              hipStream_t stream) {
  const float* PSIG = (const float*)d_in[1];
  const float* Q    = (const float*)d_in[2];
  const float* CT   = (const float*)d_in[3];

  float* ws = (float*)d_ws;
  size_t f0 = (size_t)NB * N0 * N0;
  float* pA = ws;
  float* pB = pA + f0;
  float* q1 = pB + f0;

  dim3 blk(32, 8, 1), grd(17, 17, NB);

  // cycle 1
  drelaxR_k<<<grd, blk, 0, stream>>>(PSIG, Q, pA, q1);
  drelaxU_k<<<grd, blk, 0, stream>>>(pA, Q, q1, pB);
  // cycle 2
  drelaxR_k<<<grd, blk, 0, stream>>>(pB, Q, pA, q1);

  float* psi_out = (float*)d_out;
  float* qf_out  = psi_out + f0;
  mega_k<<<grd, blk, 0, stream>>>(pA, Q, q1, CT, psi_out, qf_out);
}

// Round 5
// 117.250 us; speedup vs baseline: 3.5247x; 1.0839x over previous
//
#include <hip/hip_runtime.h>

// qg_flux, round 5: 3 dispatches.
//   K1 drelaxR: psi0 = relax^2(PSIG, q0), q1a = rescale(psi0)   [cycle-1 down]
//   K2 vleg:    pB = relax^4(pA + up(p1(q1a))), q1b = rescale(pB)
//               [cycle-1 up + cycle-2 down fused -> kills the pB..pA round-trip]
//   K3 mega:    relax^2(pB + up(p1(q1b))) + flux epilogue -> outputs
// Interior/edge block template; branchless prolong; H0SQ folded (exact po2).

#define N0 513
#define N1 257
#define NB 16

#define C0F ((float)(1.0 / 4.006103515625))
#define D0F 4.006103515625f
#define C1F ((float)(1.0 / 4.0244140625))
#define H0SQ 3.814697265625e-06f            // h0^2 = 2^-18, exact
#define INV_DX2 262144.0f
#define CENTER  1048576.0f
#define INV12S  ((float)(262144.0 / 12.0 * 262144.0))  // INV12 * 2^18

// ---------------------------------------------------------------- drelaxR ---
template<bool INT>
__device__ __forceinline__ void drelaxR_body(
    const float* __restrict__ P, const float* __restrict__ Q,
    float* __restrict__ outp, float* __restrict__ q1p,
    int ti, int tj, int ic0, int jc0, size_t base, size_t cbase, int lid,
    float* __restrict__ sIn, float* __restrict__ sQ,
    float* __restrict__ sT, float* __restrict__ sP) {
  const int n = N0;
  for (int t = lid; t < 38 * 38; t += 256) {
    int r = t / 38, c = t - r * 38;
    int gi = ti - 3 + r, gj = tj - 3 + c;
    float v;
    if constexpr (INT) v = P[(size_t)gi * n + gj];
    else v = (gi >= 0 && gi < n && gj >= 0 && gj < n) ? P[(size_t)gi * n + gj] : 0.f;
    sIn[r * 39 + c] = v;
  }
  for (int t = lid; t < 36 * 36; t += 256) {
    int r = t / 36, c = t - r * 36;
    int gi = ti - 2 + r, gj = tj - 2 + c;
    float v;
    if constexpr (INT) v = Q[(size_t)gi * n + gj] * H0SQ;
    else v = (gi >= 0 && gi < n && gj >= 0 && gj < n) ? Q[(size_t)gi * n + gj] * H0SQ : 0.f;
    sQ[r * 37 + c] = v;
  }
  __syncthreads();
  for (int t = lid; t < 36 * 36; t += 256) {
    int r = t / 36, c = t - r * 36;
    float v = 0.f;
    if (INT || ((ti - 2 + r) >= 1 && (ti - 2 + r) < n - 1 && (tj - 2 + c) >= 1 && (tj - 2 + c) < n - 1))
      v = C0F * (sIn[r * 39 + c + 1] + sIn[(r + 2) * 39 + c + 1] +
                 sIn[(r + 1) * 39 + c] + sIn[(r + 1) * 39 + c + 2] - sQ[r * 37 + c]);
    sT[r * 37 + c] = v;
  }
  __syncthreads();
  // sP aliases sIn (sIn dead after sweep1; barrier above separates)
  for (int t = lid; t < 34 * 34; t += 256) {
    int r = t / 34, c = t - r * 34;
    float v = 0.f;
    if (INT || ((ti - 1 + r) >= 1 && (ti - 1 + r) < n - 1 && (tj - 1 + c) >= 1 && (tj - 1 + c) < n - 1))
      v = C0F * (sT[r * 37 + c + 1] + sT[(r + 2) * 37 + c + 1] +
                 sT[(r + 1) * 37 + c] + sT[(r + 1) * 37 + c + 2] - sQ[(r + 1) * 37 + c + 1]);
    sP[r * 35 + c] = v;
  }
  __syncthreads();
  int tx = lid & 31, ty = lid >> 5;
  #pragma unroll
  for (int s = 0; s < 4; s++) {
    int yy = ty + 8 * s;
    int i = ti + yy, j = tj + tx;
    if (INT || (i < n && j < n))
      outp[base + (size_t)i * n + j] = sP[(yy + 1) * 35 + tx + 1];
  }
  {
    int cy = lid >> 4, cx = lid & 15;
    int ic = ic0 + cy, jc = jc0 + cx;
    if constexpr (INT) {
      int r = 2 * cy + 1, c = 2 * cx + 1;
      float v = 4.f * (D0F * sP[r * 35 + c] - sP[(r - 1) * 35 + c] - sP[(r + 1) * 35 + c]
                       - sP[r * 35 + c - 1] - sP[r * 35 + c + 1] + sQ[(r + 1) * 37 + c + 1]);
      q1p[cbase + (size_t)ic * N1 + jc] = v;
    } else {
      if (ic < N1 && jc < N1) {
        float v = 0.f;
        if (ic >= 1 && ic < N1 - 1 && jc >= 1 && jc < N1 - 1) {
          int r = 2 * cy + 1, c = 2 * cx + 1;
          v = 4.f * (D0F * sP[r * 35 + c] - sP[(r - 1) * 35 + c] - sP[(r + 1) * 35 + c]
                     - sP[r * 35 + c - 1] - sP[r * 35 + c + 1] + sQ[(r + 1) * 37 + c + 1]);
        }
        q1p[cbase + (size_t)ic * N1 + jc] = v;
      }
    }
  }
}

__global__ __launch_bounds__(256) void drelaxR_k(
    const float* __restrict__ psi, const float* __restrict__ Qg,
    float* __restrict__ out, float* __restrict__ q1) {
  __shared__ float smem[38 * 39 + 36 * 37 + 36 * 37];
  float* sIn = smem;
  float* sQ  = smem + 38 * 39;
  float* sT  = sQ + 36 * 37;
  float* sP  = smem;               // alias sIn
  int bx = blockIdx.x, by = blockIdx.y;
  int ti = by * 32, tj = bx * 32;
  size_t base = (size_t)blockIdx.z * (N0 * N0);
  size_t cbase = (size_t)blockIdx.z * (N1 * N1);
  int lid = threadIdx.y * 32 + threadIdx.x;
  bool inter = (bx >= 1 && bx <= 14 && by >= 1 && by <= 14);
  if (inter)
    drelaxR_body<true>(psi + base, Qg + base, out, q1, ti, tj, 16 * by, 16 * bx,
                       base, cbase, lid, sIn, sQ, sT, sP);
  else
    drelaxR_body<false>(psi + base, Qg + base, out, q1, ti, tj, 16 * by, 16 * bx,
                        base, cbase, lid, sIn, sQ, sT, sP);
}

// ------------------------------------------------------------------- vleg ---
// relax^4(pA + up(p1)) + rescale. Buffers:
//   A: v (42x43, org ti-5)      -> s3 (36x37, org ti-2)
//   B: q0 scaled (40x41, org ti-4)
//   C: s1 (40x41, org ti-4)     -> s4 (34x35, org ti-1)
//   D: sq1(25x26)+sp1(23x24)    -> s2 (38x39, org ti-3)
template<bool INT>
__device__ __forceinline__ void vleg_body(
    const float* __restrict__ P, const float* __restrict__ Q,
    const float* __restrict__ q1, float* __restrict__ outp, float* __restrict__ q1o,
    int ti, int tj, int c0i, int c0j, int ic0, int jc0,
    size_t base, size_t cbase, int lid,
    float* __restrict__ bufA, float* __restrict__ bufB,
    float* __restrict__ bufC, float* __restrict__ bufD) {
  const int n = N0;
  float* sq1 = bufD;            // [25][26] coarse org c0-1
  float* sp1 = bufD + 25 * 26;  // [23][24] coarse org c0
  for (int t = lid; t < 25 * 25; t += 256) {
    int r = t / 25, c = t - r * 25;
    int ci = c0i - 1 + r, cj = c0j - 1 + c;
    float v;
    if constexpr (INT) v = q1[(size_t)ci * N1 + cj];
    else v = (ci >= 0 && ci < N1 && cj >= 0 && cj < N1) ? q1[(size_t)ci * N1 + cj] : 0.f;
    sq1[r * 26 + c] = v;
  }
  for (int t = lid; t < 40 * 40; t += 256) {
    int r = t / 40, c = t - r * 40;
    int gi = ti - 4 + r, gj = tj - 4 + c;
    float v;
    if constexpr (INT) v = Q[(size_t)gi * n + gj] * H0SQ;
    else v = (gi >= 0 && gi < n && gj >= 0 && gj < n) ? Q[(size_t)gi * n + gj] * H0SQ : 0.f;
    bufB[r * 41 + c] = v;
  }
  __syncthreads();
  for (int t = lid; t < 23 * 23; t += 256) {   // p1 = relax(relax(0,q1),q1)
    int r = t / 23, c = t - r * 23;
    float v = 0.f;
    if (INT || ((c0i + r) >= 1 && (c0i + r) < N1 - 1 && (c0j + c) >= 1 && (c0j + c) < N1 - 1))
      v = C1F * (-C1F * (sq1[r * 26 + c + 1] + sq1[(r + 2) * 26 + c + 1] +
                         sq1[(r + 1) * 26 + c] + sq1[(r + 1) * 26 + c + 2])
                 - sq1[(r + 1) * 26 + c + 1]);
    sp1[r * 24 + c] = v;
  }
  __syncthreads();
  for (int t = lid; t < 42 * 42; t += 256) {   // v = pA + up(p1) -> A
    int r = t / 42, c = t - r * 42;
    int gi = ti - 5 + r, gj = tj - 5 + c;
    float v = 0.f;
    if (INT || (gi >= 0 && gi < n && gj >= 0 && gj < n)) {
      int r1 = (gi >> 1) - c0i, c1 = (gj >> 1) - c0j;
      float a = sp1[r1 * 24 + c1],       b = sp1[r1 * 24 + c1 + 1];
      float e = sp1[(r1 + 1) * 24 + c1], d = sp1[(r1 + 1) * 24 + c1 + 1];
      float wx = (gj & 1) ? 0.5f : 0.f, wy = (gi & 1) ? 0.5f : 0.f;
      float r0 = a + wx * (b - a), rr = e + wx * (d - e);
      v = P[(size_t)gi * n + gj] + (r0 + wy * (rr - r0));
    }
    bufA[r * 43 + c] = v;
  }
  __syncthreads();
  for (int t = lid; t < 40 * 40; t += 256) {   // s1 -> C (org ti-4)
    int r = t / 40, c = t - r * 40;
    float v = 0.f;
    if (INT || ((ti - 4 + r) >= 1 && (ti - 4 + r) < n - 1 && (tj - 4 + c) >= 1 && (tj - 4 + c) < n - 1))
      v = C0F * (bufA[r * 43 + c + 1] + bufA[(r + 2) * 43 + c + 1] +
                 bufA[(r + 1) * 43 + c] + bufA[(r + 1) * 43 + c + 2] - bufB[r * 41 + c]);
    bufC[r * 41 + c] = v;
  }
  __syncthreads();
  for (int t = lid; t < 38 * 38; t += 256) {   // s2 -> D (org ti-3); sq1/sp1 dead
    int r = t / 38, c = t - r * 38;
    float v = 0.f;
    if (INT || ((ti - 3 + r) >= 1 && (ti - 3 + r) < n - 1 && (tj - 3 + c) >= 1 && (tj - 3 + c) < n - 1))
      v = C0F * (bufC[r * 41 + c + 1] + bufC[(r + 2) * 41 + c + 1] +
                 bufC[(r + 1) * 41 + c] + bufC[(r + 1) * 41 + c + 2] - bufB[(r + 1) * 41 + c + 1]);
    bufD[r * 39 + c] = v;
  }
  __syncthreads();
  for (int t = lid; t < 36 * 36; t += 256) {   // s3 -> A (org ti-2); v dead
    int r = t / 36, c = t - r * 36;
    float v = 0.f;
    if (INT || ((ti - 2 + r) >= 1 && (ti - 2 + r) < n - 1 && (tj - 2 + c) >= 1 && (tj - 2 + c) < n - 1))
      v = C0F * (bufD[r * 39 + c + 1] + bufD[(r + 2) * 39 + c + 1] +
                 bufD[(r + 1) * 39 + c] + bufD[(r + 1) * 39 + c + 2] - bufB[(r + 2) * 41 + c + 2]);
    bufA[r * 37 + c] = v;
  }
  __syncthreads();
  for (int t = lid; t < 34 * 34; t += 256) {   // s4 -> C (org ti-1); s1 dead
    int r = t / 34, c = t - r * 34;
    float v = 0.f;
    if (INT || ((ti - 1 + r) >= 1 && (ti - 1 + r) < n - 1 && (tj - 1 + c) >= 1 && (tj - 1 + c) < n - 1))
      v = C0F * (bufA[r * 37 + c + 1] + bufA[(r + 2) * 37 + c + 1] +
                 bufA[(r + 1) * 37 + c] + bufA[(r + 1) * 37 + c + 2] - bufB[(r + 3) * 41 + c + 3]);
    bufC[r * 35 + c] = v;
  }
  __syncthreads();
  int tx = lid & 31, ty = lid >> 5;
  #pragma unroll
  for (int s = 0; s < 4; s++) {
    int yy = ty + 8 * s;
    int i = ti + yy, j = tj + tx;
    if (INT || (i < n && j < n))
      outp[base + (size_t)i * n + j] = bufC[(yy + 1) * 35 + tx + 1];
  }
  {
    int cy = lid >> 4, cx = lid & 15;
    int ic = ic0 + cy, jc = jc0 + cx;
    if constexpr (INT) {
      int r = 2 * cy + 1, c = 2 * cx + 1;  // bufC local of (2ic,2jc)
      float v = 4.f * (D0F * bufC[r * 35 + c] - bufC[(r - 1) * 35 + c] - bufC[(r + 1) * 35 + c]
                       - bufC[r * 35 + c - 1] - bufC[r * 35 + c + 1]
                       + bufB[(2 * cy + 4) * 41 + 2 * cx + 4]);
      q1o[cbase + (size_t)ic * N1 + jc] = v;
    } else {
      if (ic < N1 && jc < N1) {
        float v = 0.f;
        if (ic >= 1 && ic < N1 - 1 && jc >= 1 && jc < N1 - 1) {
          int r = 2 * cy + 1, c = 2 * cx + 1;
          v = 4.f * (D0F * bufC[r * 35 + c] - bufC[(r - 1) * 35 + c] - bufC[(r + 1) * 35 + c]
                     - bufC[r * 35 + c - 1] - bufC[r * 35 + c + 1]
                     + bufB[(2 * cy + 4) * 41 + 2 * cx + 4]);
        }
        q1o[cbase + (size_t)ic * N1 + jc] = v;
      }
    }
  }
}

__global__ __launch_bounds__(256) void vleg_k(
    const float* __restrict__ psi, const float* __restrict__ Qg,
    const float* __restrict__ q1g, float* __restrict__ out, float* __restrict__ q1o) {
  __shared__ float bufA[42 * 43];
  __shared__ float bufB[40 * 41];
  __shared__ float bufC[40 * 41];
  __shared__ float bufD[38 * 39];
  int bx = blockIdx.x, by = blockIdx.y;
  int ti = by * 32, tj = bx * 32;
  int c0i = 16 * by - 3, c0j = 16 * bx - 3;
  size_t base = (size_t)blockIdx.z * (N0 * N0);
  size_t cbase = (size_t)blockIdx.z * (N1 * N1);
  const float* q1 = q1g + cbase;
  int lid = threadIdx.y * 32 + threadIdx.x;
  bool inter = (bx >= 1 && bx <= 14 && by >= 1 && by <= 14);
  if (inter)
    vleg_body<true>(psi + base, Qg + base, q1, out, q1o, ti, tj, c0i, c0j,
                    16 * by, 16 * bx, base, cbase, lid, bufA, bufB, bufC, bufD);
  else
    vleg_body<false>(psi + base, Qg + base, q1, out, q1o, ti, tj, c0i, c0j,
                     16 * by, 16 * bx, base, cbase, lid, bufA, bufB, bufC, bufD);
}

// ------------------------------------------------------------------- mega ---
template<bool INT>
__device__ __forceinline__ void mega_body(
    const float* __restrict__ P, const float* __restrict__ Q,
    const float* __restrict__ q1, const float* __restrict__ CT,
    float* __restrict__ psi_out, float* __restrict__ qf_out,
    int ti, int tj, int c0i, int c0j, size_t base, int lid,
    float* __restrict__ bufA, float* __restrict__ bufB,
    float* __restrict__ bufC, float* __restrict__ bufD) {
  const int n = N0;
  float* sq1 = bufD;
  float* sp1 = bufD + 25 * 26;
  for (int t = lid; t < 25 * 25; t += 256) {
    int r = t / 25, c = t - r * 25;
    int ci = c0i - 1 + r, cj = c0j - 1 + c;
    float v;
    if constexpr (INT) v = q1[(size_t)ci * N1 + cj];
    else v = (ci >= 0 && ci < N1 && cj >= 0 && cj < N1) ? q1[(size_t)ci * N1 + cj] : 0.f;
    sq1[r * 26 + c] = v;
  }
  for (int t = lid; t < 40 * 40; t += 256) {
    int r = t / 40, c = t - r * 40;
    int gi = ti - 4 + r, gj = tj - 4 + c;
    float v;
    if constexpr (INT) v = Q[(size_t)gi * n + gj] * H0SQ;
    else v = (gi >= 0 && gi < n && gj >= 0 && gj < n) ? Q[(size_t)gi * n + gj] * H0SQ : 0.f;
    bufB[r * 41 + c] = v;
  }
  __syncthreads();
  for (int t = lid; t < 23 * 23; t += 256) {
    int r = t / 23, c = t - r * 23;
    float v = 0.f;
    if (INT || ((c0i + r) >= 1 && (c0i + r) < N1 - 1 && (c0j + c) >= 1 && (c0j + c) < N1 - 1))
      v = C1F * (-C1F * (sq1[r * 26 + c + 1] + sq1[(r + 2) * 26 + c + 1] +
                         sq1[(r + 1) * 26 + c] + sq1[(r + 1) * 26 + c + 2])
                 - sq1[(r + 1) * 26 + c + 1]);
    sp1[r * 24 + c] = v;
  }
  __syncthreads();
  for (int t = lid; t < 42 * 42; t += 256) {
    int r = t / 42, c = t - r * 42;
    int gi = ti - 5 + r, gj = tj - 5 + c;
    float v = 0.f;
    if (INT || (gi >= 0 && gi < n && gj >= 0 && gj < n)) {
      int r1 = (gi >> 1) - c0i, c1 = (gj >> 1) - c0j;
      float a = sp1[r1 * 24 + c1],       b = sp1[r1 * 24 + c1 + 1];
      float e = sp1[(r1 + 1) * 24 + c1], d = sp1[(r1 + 1) * 24 + c1 + 1];
      float wx = (gj & 1) ? 0.5f : 0.f, wy = (gi & 1) ? 0.5f : 0.f;
      float r0 = a + wx * (b - a), rr = e + wx * (d - e);
      v = P[(size_t)gi * n + gj] + (r0 + wy * (rr - r0));
    }
    bufA[r * 43 + c] = v;
  }
  __syncthreads();
  for (int t = lid; t < 40 * 40; t += 256) {
    int r = t / 40, c = t - r * 40;
    float v = 0.f;
    if (INT || ((ti - 4 + r) >= 1 && (ti - 4 + r) < n - 1 && (tj - 4 + c) >= 1 && (tj - 4 + c) < n - 1))
      v = C0F * (bufA[r * 43 + c + 1] + bufA[(r + 2) * 43 + c + 1] +
                 bufA[(r + 1) * 43 + c] + bufA[(r + 1) * 43 + c + 2] - bufB[r * 41 + c]);
    bufC[r * 41 + c] = v;
  }
  __syncthreads();
  for (int t = lid; t < 38 * 38; t += 256) {
    int r = t / 38, c = t - r * 38;
    float v = 0.f;
    if (INT || ((ti - 3 + r) >= 1 && (ti - 3 + r) < n - 1 && (tj - 3 + c) >= 1 && (tj - 3 + c) < n - 1))
      v = C0F * (bufC[r * 41 + c + 1] + bufC[(r + 2) * 41 + c + 1] +
                 bufC[(r + 1) * 41 + c] + bufC[(r + 1) * 41 + c + 2] - bufB[(r + 1) * 41 + c + 1]);
    bufD[r * 39 + c] = v;
  }
  __syncthreads();
  for (int t = lid; t < 36 * 36; t += 256) {
    int r = t / 36, c = t - r * 36;
    float v = 0.f;
    if (INT || ((ti - 2 + r) >= 1 && (ti - 2 + r) < n - 1 && (tj - 2 + c) >= 1 && (tj - 2 + c) < n - 1))
      v = (bufD[r * 39 + c + 1] + bufD[(r + 2) * 39 + c + 1] +
           bufD[(r + 1) * 39 + c] + bufD[(r + 1) * 39 + c + 2]) * INV_DX2
          - bufD[(r + 1) * 39 + c + 1] * CENTER;
    bufA[r * 37 + c] = v;
  }
  __syncthreads();
  for (int t = lid; t < 34 * 34; t += 256) {
    int r = t / 34, c = t - r * 34;
    float v = 0.f;
    if (INT || ((ti - 1 + r) >= 1 && (ti - 1 + r) < n - 1 && (tj - 1 + c) >= 1 && (tj - 1 + c) < n - 1))
      v = (bufA[r * 37 + c + 1] + bufA[(r + 2) * 37 + c + 1] +
           bufA[(r + 1) * 37 + c] + bufA[(r + 1) * 37 + c + 2]) * INV_DX2
          - bufA[(r + 1) * 37 + c + 1] * CENTER;
    bufC[r * 35 + c] = v;
  }
  __syncthreads();
  int tx = lid & 31, ty = lid >> 5;
  #pragma unroll
  for (int s = 0; s < 4; s++) {
    int yy = ty + 8 * s;
    int i = ti + yy, j = tj + tx;
    if (!INT && (i >= n || j >= n)) continue;
    size_t idx = base + (size_t)i * n + j;
    int pr = yy + 3, pc = tx + 3;
    psi_out[idx] = bufD[pr * 39 + pc];
    float qv = 0.f;
    if (INT || (i >= 1 && i < n - 1 && j >= 1 && j < n - 1)) {
      float z1v = bufA[(yy + 2) * 37 + tx + 2];
      int r2 = yy + 1, c2 = tx + 1;
      float z2v = bufC[r2 * 35 + c2];
      float z4 = (bufC[r2 * 35 + c2 - 1] + bufC[r2 * 35 + c2 + 1] +
                  bufC[(r2 - 1) * 35 + c2] + bufC[(r2 + 1) * 35 + c2]) * INV_DX2
                 - z2v * CENTER;
      float Amm = bufD[(pr - 1) * 39 + pc - 1], Am0 = bufD[(pr - 1) * 39 + pc],
            Amp = bufD[(pr - 1) * 39 + pc + 1];
      float A0m = bufD[pr * 39 + pc - 1], A0p = bufD[pr * 39 + pc + 1];
      float Apm = bufD[(pr + 1) * 39 + pc - 1], Ap0 = bufD[(pr + 1) * 39 + pc],
            App = bufD[(pr + 1) * 39 + pc + 1];
      int qr = yy + 4, qc = tx + 4;
      float J = (A0m - Am0) * bufB[(qr - 1) * 41 + qc - 1]
              + (Amm + A0m - Amp - A0p) * bufB[(qr - 1) * 41 + qc]
              + (Am0 - A0p) * bufB[(qr - 1) * 41 + qc + 1]
              + (Apm + Ap0 - Amm - Am0) * bufB[qr * 41 + qc - 1]
              + (Am0 + Amp - Ap0 - App) * bufB[qr * 41 + qc + 1]
              + (Ap0 - A0m) * bufB[(qr + 1) * 41 + qc - 1]
              + (A0p + App - A0m - Apm) * bufB[(qr + 1) * 41 + qc]
              + (A0p - Ap0) * bufB[(qr + 1) * 41 + qc + 1];
      J *= INV12S;
      float ct = CT[(size_t)i * n + j];
      qv = -J - 1e-6f * z1v + 1e-8f * z2v - 2e-11f * z4 + ct - 256.0f * (A0p - A0m);
    }
    qf_out[idx] = qv;
  }
}

__global__ __launch_bounds__(256) void mega_k(
    const float* __restrict__ psi, const float* __restrict__ Qg,
    const float* __restrict__ q1g, const float* __restrict__ CT,
    float* __restrict__ psi_out, float* __restrict__ qf_out) {
  __shared__ float bufA[42 * 43];
  __shared__ float bufB[40 * 41];
  __shared__ float bufC[40 * 41];
  __shared__ float bufD[38 * 39];
  int bx = blockIdx.x, by = blockIdx.y;
  int ti = by * 32, tj = bx * 32;
  int c0i = 16 * by - 3, c0j = 16 * bx - 3;
  size_t base = (size_t)blockIdx.z * (N0 * N0);
  const float* q1 = q1g + (size_t)blockIdx.z * (N1 * N1);
  int lid = threadIdx.y * 32 + threadIdx.x;
  bool inter = (bx >= 1 && bx <= 14 && by >= 1 && by <= 14);
  if (inter)
    mega_body<true>(psi + base, Qg + base, q1, CT, psi_out, qf_out,
                    ti, tj, c0i, c0j, base, lid, bufA, bufB, bufC, bufD);
  else
    mega_body<false>(psi + base, Qg + base, q1, CT, psi_out, qf_out,
                     ti, tj, c0i, c0j, base, lid, bufA, bufB, bufC, bufD);
}

extern "C" void kernel_launch(void* const* d_in, const int* in_sizes, int n_in,
                              void* d_out, int out_size, void* d_ws, size_t ws_size,
                              hipStream_t stream) {
  const float* PSIG = (const float*)d_in[1];
  const float* Q    = (const float*)d_in[2];
  const float* CT   = (const float*)d_in[3];

  float* ws = (float*)d_ws;
  size_t f0 = (size_t)NB * N0 * N0;
  size_t f1 = (size_t)NB * N1 * N1;
  float* pA  = ws;
  float* pB  = pA + f0;
  float* q1a = pB + f0;
  float* q1b = q1a + f1;

  dim3 blk(32, 8, 1), grd(17, 17, NB);

  drelaxR_k<<<grd, blk, 0, stream>>>(PSIG, Q, pA, q1a);      // cycle-1 down
  vleg_k<<<grd, blk, 0, stream>>>(pA, Q, q1a, pB, q1b);      // c1 up + c2 down
  float* psi_out = (float*)d_out;
  float* qf_out  = psi_out + f0;
  mega_k<<<grd, blk, 0, stream>>>(pB, Q, q1b, CT, psi_out, qf_out);  // c2 up + flux
}

// Round 6
// 110.793 us; speedup vs baseline: 3.7302x; 1.0583x over previous
//
#include <hip/hip_runtime.h>

// qg_flux, round 6: 3 dispatches, 512-thread (8-wave) blocks, composite
// double-relax (13-point) in interior blocks. Edge blocks keep the exact
// two-stage path. Structure:
//   K1 drelaxR: psi0 = relax^2(PSIG,q0), q1a = rescale(psi0)
//   K2 vleg:    pB = relax^4(pA + up(p1(q1a))), q1b = rescale(pB)
//   K3 mega:    relax^2(pB + up(p1(q1b))) + flux epilogue -> outputs

#define N0 513
#define N1 257
#define NB 16
#define NT 512

#define C0F ((float)(1.0 / 4.006103515625))
#define D0F 4.006103515625f
#define C1F ((float)(1.0 / 4.0244140625))
#define H0SQ 3.814697265625e-06f            // h0^2 = 2^-18, exact
#define INV_DX2 262144.0f
#define CENTER  1048576.0f
#define INV12S  ((float)(262144.0 / 12.0 * 262144.0))  // INV12 * 2^18

// composite relax^2 inner sum: u = center ptr (stride su), qq = center q ptr
// (stride sq). Valid only when all 4 sweep-1 neighbors are interior.
__device__ __forceinline__ float relax2c(const float* u, int su,
                                         const float* qq, int sq) {
  float X = 4.f * u[0]
          + (u[-2 * su] + u[2 * su] + u[-2] + u[2])
          + 2.f * (u[-su - 1] + u[-su + 1] + u[su - 1] + u[su + 1])
          - (qq[-sq] + qq[sq] + qq[-1] + qq[1]);
  return C0F * (C0F * X - qq[0]);
}

// ---------------------------------------------------------------- drelaxR ---
template<bool INT>
__device__ __forceinline__ void drelaxR_body(
    const float* __restrict__ P, const float* __restrict__ Q,
    float* __restrict__ outp, float* __restrict__ q1p,
    int ti, int tj, int ic0, int jc0, size_t base, size_t cbase, int lid,
    float* __restrict__ sIn, float* __restrict__ sQ,
    float* __restrict__ sT, float* __restrict__ sP) {
  const int n = N0;
  for (int t = lid; t < 38 * 38; t += NT) {
    int r = t / 38, c = t - r * 38;
    int gi = ti - 3 + r, gj = tj - 3 + c;
    float v;
    if constexpr (INT) v = P[(size_t)gi * n + gj];
    else v = (gi >= 0 && gi < n && gj >= 0 && gj < n) ? P[(size_t)gi * n + gj] : 0.f;
    sIn[r * 39 + c] = v;
  }
  for (int t = lid; t < 36 * 36; t += NT) {
    int r = t / 36, c = t - r * 36;
    int gi = ti - 2 + r, gj = tj - 2 + c;
    float v;
    if constexpr (INT) v = Q[(size_t)gi * n + gj] * H0SQ;
    else v = (gi >= 0 && gi < n && gj >= 0 && gj < n) ? Q[(size_t)gi * n + gj] * H0SQ : 0.f;
    sQ[r * 37 + c] = v;
  }
  __syncthreads();
  if constexpr (INT) {
    // composite relax^2: sIn(org-3) -> sP(org-1), 34x34
    for (int t = lid; t < 34 * 34; t += NT) {
      int r = t / 34, c = t - r * 34;
      sP[r * 35 + c] = relax2c(&sIn[(r + 2) * 39 + c + 2], 39,
                               &sQ[(r + 1) * 37 + c + 1], 37);
    }
    __syncthreads();
  } else {
    for (int t = lid; t < 36 * 36; t += NT) {
      int r = t / 36, c = t - r * 36;
      float v = 0.f;
      if ((ti - 2 + r) >= 1 && (ti - 2 + r) < n - 1 && (tj - 2 + c) >= 1 && (tj - 2 + c) < n - 1)
        v = C0F * (sIn[r * 39 + c + 1] + sIn[(r + 2) * 39 + c + 1] +
                   sIn[(r + 1) * 39 + c] + sIn[(r + 1) * 39 + c + 2] - sQ[r * 37 + c]);
      sT[r * 37 + c] = v;
    }
    __syncthreads();
    for (int t = lid; t < 34 * 34; t += NT) {
      int r = t / 34, c = t - r * 34;
      float v = 0.f;
      if ((ti - 1 + r) >= 1 && (ti - 1 + r) < n - 1 && (tj - 1 + c) >= 1 && (tj - 1 + c) < n - 1)
        v = C0F * (sT[r * 37 + c + 1] + sT[(r + 2) * 37 + c + 1] +
                   sT[(r + 1) * 37 + c] + sT[(r + 1) * 37 + c + 2] - sQ[(r + 1) * 37 + c + 1]);
      sP[r * 35 + c] = v;
    }
    __syncthreads();
  }
  int tx = lid & 31, ty = lid >> 5;
  #pragma unroll
  for (int s = 0; s < 2; s++) {
    int yy = ty + 16 * s;
    int i = ti + yy, j = tj + tx;
    if (INT || (i < n && j < n))
      outp[base + (size_t)i * n + j] = sP[(yy + 1) * 35 + tx + 1];
  }
  if (lid < 256) {
    int cy = lid >> 4, cx = lid & 15;
    int ic = ic0 + cy, jc = jc0 + cx;
    if constexpr (INT) {
      int r = 2 * cy + 1, c = 2 * cx + 1;
      float v = 4.f * (D0F * sP[r * 35 + c] - sP[(r - 1) * 35 + c] - sP[(r + 1) * 35 + c]
                       - sP[r * 35 + c - 1] - sP[r * 35 + c + 1] + sQ[(r + 1) * 37 + c + 1]);
      q1p[cbase + (size_t)ic * N1 + jc] = v;
    } else {
      if (ic < N1 && jc < N1) {
        float v = 0.f;
        if (ic >= 1 && ic < N1 - 1 && jc >= 1 && jc < N1 - 1) {
          int r = 2 * cy + 1, c = 2 * cx + 1;
          v = 4.f * (D0F * sP[r * 35 + c] - sP[(r - 1) * 35 + c] - sP[(r + 1) * 35 + c]
                     - sP[r * 35 + c - 1] - sP[r * 35 + c + 1] + sQ[(r + 1) * 37 + c + 1]);
        }
        q1p[cbase + (size_t)ic * N1 + jc] = v;
      }
    }
  }
}

__global__ __launch_bounds__(NT) void drelaxR_k(
    const float* __restrict__ psi, const float* __restrict__ Qg,
    float* __restrict__ out, float* __restrict__ q1) {
  __shared__ float sIn[38 * 39], sQ[36 * 37], sT[36 * 37], sP[34 * 35];
  int bx = blockIdx.x, by = blockIdx.y;
  int ti = by * 32, tj = bx * 32;
  size_t base = (size_t)blockIdx.z * (N0 * N0);
  size_t cbase = (size_t)blockIdx.z * (N1 * N1);
  int lid = threadIdx.y * 32 + threadIdx.x;
  bool inter = (bx >= 1 && bx <= 14 && by >= 1 && by <= 14);
  if (inter)
    drelaxR_body<true>(psi + base, Qg + base, out, q1, ti, tj, 16 * by, 16 * bx,
                       base, cbase, lid, sIn, sQ, sT, sP);
  else
    drelaxR_body<false>(psi + base, Qg + base, out, q1, ti, tj, 16 * by, 16 * bx,
                        base, cbase, lid, sIn, sQ, sT, sP);
}

// ------------------------------------------------------- shared coarse prep --
// stage sq1(25x26@c0-1) + q0(40x41@ti-4, scaled); then p1(23x24@c0); then
// v = P + up(p1) (42x43@ti-5) into bufA.
template<bool INT>
__device__ __forceinline__ void coarse_and_v(
    const float* __restrict__ P, const float* __restrict__ Q,
    const float* __restrict__ q1,
    int ti, int tj, int c0i, int c0j, int lid,
    float* __restrict__ bufA, float* __restrict__ bufB,
    float* __restrict__ sq1, float* __restrict__ sp1) {
  const int n = N0;
  for (int t = lid; t < 25 * 25; t += NT) {
    int r = t / 25, c = t - r * 25;
    int ci = c0i - 1 + r, cj = c0j - 1 + c;
    float v;
    if constexpr (INT) v = q1[(size_t)ci * N1 + cj];
    else v = (ci >= 0 && ci < N1 && cj >= 0 && cj < N1) ? q1[(size_t)ci * N1 + cj] : 0.f;
    sq1[r * 26 + c] = v;
  }
  for (int t = lid; t < 40 * 40; t += NT) {
    int r = t / 40, c = t - r * 40;
    int gi = ti - 4 + r, gj = tj - 4 + c;
    float v;
    if constexpr (INT) v = Q[(size_t)gi * n + gj] * H0SQ;
    else v = (gi >= 0 && gi < n && gj >= 0 && gj < n) ? Q[(size_t)gi * n + gj] * H0SQ : 0.f;
    bufB[r * 41 + c] = v;
  }
  __syncthreads();
  for (int t = lid; t < 23 * 23; t += NT) {
    int r = t / 23, c = t - r * 23;
    float v = 0.f;
    if (INT || ((c0i + r) >= 1 && (c0i + r) < N1 - 1 && (c0j + c) >= 1 && (c0j + c) < N1 - 1))
      v = C1F * (-C1F * (sq1[r * 26 + c + 1] + sq1[(r + 2) * 26 + c + 1] +
                         sq1[(r + 1) * 26 + c] + sq1[(r + 1) * 26 + c + 2])
                 - sq1[(r + 1) * 26 + c + 1]);
    sp1[r * 24 + c] = v;
  }
  __syncthreads();
  for (int t = lid; t < 42 * 42; t += NT) {
    int r = t / 42, c = t - r * 42;
    int gi = ti - 5 + r, gj = tj - 5 + c;
    float v = 0.f;
    if (INT || (gi >= 0 && gi < n && gj >= 0 && gj < n)) {
      int r1 = (gi >> 1) - c0i, c1 = (gj >> 1) - c0j;
      float a = sp1[r1 * 24 + c1],       b = sp1[r1 * 24 + c1 + 1];
      float e = sp1[(r1 + 1) * 24 + c1], d = sp1[(r1 + 1) * 24 + c1 + 1];
      float wx = (gj & 1) ? 0.5f : 0.f, wy = (gi & 1) ? 0.5f : 0.f;
      float r0 = a + wx * (b - a), rr = e + wx * (d - e);
      v = P[(size_t)gi * n + gj] + (r0 + wy * (rr - r0));
    }
    bufA[r * 43 + c] = v;
  }
  __syncthreads();
}

// ------------------------------------------------------------------- vleg ---
template<bool INT>
__device__ __forceinline__ void vleg_body(
    const float* __restrict__ P, const float* __restrict__ Q,
    const float* __restrict__ q1, float* __restrict__ outp, float* __restrict__ q1o,
    int ti, int tj, int c0i, int c0j, int ic0, int jc0,
    size_t base, size_t cbase, int lid,
    float* __restrict__ bufA, float* __restrict__ bufB,
    float* __restrict__ bufC, float* __restrict__ bufD) {
  const int n = N0;
  coarse_and_v<INT>(P, Q, q1, ti, tj, c0i, c0j, lid, bufA, bufB, bufD, bufD + 25 * 26);
  if constexpr (INT) {
    // composite1: bufA(org-5) -> bufD (38x38, org-3)
    for (int t = lid; t < 38 * 38; t += NT) {
      int r = t / 38, c = t - r * 38;
      bufD[r * 39 + c] = relax2c(&bufA[(r + 2) * 43 + c + 2], 43,
                                 &bufB[(r + 1) * 41 + c + 1], 41);
    }
    __syncthreads();
    // composite2: bufD(org-3) -> bufC stride35 (34x34, org-1)
    for (int t = lid; t < 34 * 34; t += NT) {
      int r = t / 34, c = t - r * 34;
      bufC[r * 35 + c] = relax2c(&bufD[(r + 2) * 39 + c + 2], 39,
                                 &bufB[(r + 3) * 41 + c + 3], 41);
    }
    __syncthreads();
  } else {
    for (int t = lid; t < 40 * 40; t += NT) {   // s1 -> C41 (org-4)
      int r = t / 40, c = t - r * 40;
      float v = 0.f;
      if ((ti - 4 + r) >= 1 && (ti - 4 + r) < n - 1 && (tj - 4 + c) >= 1 && (tj - 4 + c) < n - 1)
        v = C0F * (bufA[r * 43 + c + 1] + bufA[(r + 2) * 43 + c + 1] +
                   bufA[(r + 1) * 43 + c] + bufA[(r + 1) * 43 + c + 2] - bufB[r * 41 + c]);
      bufC[r * 41 + c] = v;
    }
    __syncthreads();
    for (int t = lid; t < 38 * 38; t += NT) {   // s2 -> D (org-3)
      int r = t / 38, c = t - r * 38;
      float v = 0.f;
      if ((ti - 3 + r) >= 1 && (ti - 3 + r) < n - 1 && (tj - 3 + c) >= 1 && (tj - 3 + c) < n - 1)
        v = C0F * (bufC[r * 41 + c + 1] + bufC[(r + 2) * 41 + c + 1] +
                   bufC[(r + 1) * 41 + c] + bufC[(r + 1) * 41 + c + 2] - bufB[(r + 1) * 41 + c + 1]);
      bufD[r * 39 + c] = v;
    }
    __syncthreads();
    for (int t = lid; t < 36 * 36; t += NT) {   // s3 -> A37 (org-2)
      int r = t / 36, c = t - r * 36;
      float v = 0.f;
      if ((ti - 2 + r) >= 1 && (ti - 2 + r) < n - 1 && (tj - 2 + c) >= 1 && (tj - 2 + c) < n - 1)
        v = C0F * (bufD[r * 39 + c + 1] + bufD[(r + 2) * 39 + c + 1] +
                   bufD[(r + 1) * 39 + c] + bufD[(r + 1) * 39 + c + 2] - bufB[(r + 2) * 41 + c + 2]);
      bufA[r * 37 + c] = v;
    }
    __syncthreads();
    for (int t = lid; t < 34 * 34; t += NT) {   // s4 -> C35 (org-1)
      int r = t / 34, c = t - r * 34;
      float v = 0.f;
      if ((ti - 1 + r) >= 1 && (ti - 1 + r) < n - 1 && (tj - 1 + c) >= 1 && (tj - 1 + c) < n - 1)
        v = C0F * (bufA[r * 37 + c + 1] + bufA[(r + 2) * 37 + c + 1] +
                   bufA[(r + 1) * 37 + c] + bufA[(r + 1) * 37 + c + 2] - bufB[(r + 3) * 41 + c + 3]);
      bufC[r * 35 + c] = v;
    }
    __syncthreads();
  }
  int tx = lid & 31, ty = lid >> 5;
  #pragma unroll
  for (int s = 0; s < 2; s++) {
    int yy = ty + 16 * s;
    int i = ti + yy, j = tj + tx;
    if (INT || (i < n && j < n))
      outp[base + (size_t)i * n + j] = bufC[(yy + 1) * 35 + tx + 1];
  }
  if (lid < 256) {
    int cy = lid >> 4, cx = lid & 15;
    int ic = ic0 + cy, jc = jc0 + cx;
    if constexpr (INT) {
      int r = 2 * cy + 1, c = 2 * cx + 1;
      float v = 4.f * (D0F * bufC[r * 35 + c] - bufC[(r - 1) * 35 + c] - bufC[(r + 1) * 35 + c]
                       - bufC[r * 35 + c - 1] - bufC[r * 35 + c + 1]
                       + bufB[(2 * cy + 4) * 41 + 2 * cx + 4]);
      q1o[cbase + (size_t)ic * N1 + jc] = v;
    } else {
      if (ic < N1 && jc < N1) {
        float v = 0.f;
        if (ic >= 1 && ic < N1 - 1 && jc >= 1 && jc < N1 - 1) {
          int r = 2 * cy + 1, c = 2 * cx + 1;
          v = 4.f * (D0F * bufC[r * 35 + c] - bufC[(r - 1) * 35 + c] - bufC[(r + 1) * 35 + c]
                     - bufC[r * 35 + c - 1] - bufC[r * 35 + c + 1]
                     + bufB[(2 * cy + 4) * 41 + 2 * cx + 4]);
        }
        q1o[cbase + (size_t)ic * N1 + jc] = v;
      }
    }
  }
}

__global__ __launch_bounds__(NT) void vleg_k(
    const float* __restrict__ psi, const float* __restrict__ Qg,
    const float* __restrict__ q1g, float* __restrict__ out, float* __restrict__ q1o) {
  __shared__ float bufA[42 * 43];
  __shared__ float bufB[40 * 41];
  __shared__ float bufC[40 * 41];
  __shared__ float bufD[38 * 39];
  int bx = blockIdx.x, by = blockIdx.y;
  int ti = by * 32, tj = bx * 32;
  int c0i = 16 * by - 3, c0j = 16 * bx - 3;
  size_t base = (size_t)blockIdx.z * (N0 * N0);
  size_t cbase = (size_t)blockIdx.z * (N1 * N1);
  const float* q1 = q1g + cbase;
  int lid = threadIdx.y * 32 + threadIdx.x;
  bool inter = (bx >= 1 && bx <= 14 && by >= 1 && by <= 14);
  if (inter)
    vleg_body<true>(psi + base, Qg + base, q1, out, q1o, ti, tj, c0i, c0j,
                    16 * by, 16 * bx, base, cbase, lid, bufA, bufB, bufC, bufD);
  else
    vleg_body<false>(psi + base, Qg + base, q1, out, q1o, ti, tj, c0i, c0j,
                     16 * by, 16 * bx, base, cbase, lid, bufA, bufB, bufC, bufD);
}

// ------------------------------------------------------------------- mega ---
template<bool INT>
__device__ __forceinline__ void mega_body(
    const float* __restrict__ P, const float* __restrict__ Q,
    const float* __restrict__ q1, const float* __restrict__ CT,
    float* __restrict__ psi_out, float* __restrict__ qf_out,
    int ti, int tj, int c0i, int c0j, size_t base, int lid,
    float* __restrict__ bufA, float* __restrict__ bufB,
    float* __restrict__ bufC, float* __restrict__ bufD) {
  const int n = N0;
  coarse_and_v<INT>(P, Q, q1, ti, tj, c0i, c0j, lid, bufA, bufB, bufD, bufD + 25 * 26);
  if constexpr (INT) {
    // composite relax^2: bufA(org-5) -> bufD (sP, 38x38, org-3)
    for (int t = lid; t < 38 * 38; t += NT) {
      int r = t / 38, c = t - r * 38;
      bufD[r * 39 + c] = relax2c(&bufA[(r + 2) * 43 + c + 2], 43,
                                 &bufB[(r + 1) * 41 + c + 1], 41);
    }
    __syncthreads();
  } else {
    for (int t = lid; t < 40 * 40; t += NT) {
      int r = t / 40, c = t - r * 40;
      float v = 0.f;
      if ((ti - 4 + r) >= 1 && (ti - 4 + r) < n - 1 && (tj - 4 + c) >= 1 && (tj - 4 + c) < n - 1)
        v = C0F * (bufA[r * 43 + c + 1] + bufA[(r + 2) * 43 + c + 1] +
                   bufA[(r + 1) * 43 + c] + bufA[(r + 1) * 43 + c + 2] - bufB[r * 41 + c]);
      bufC[r * 41 + c] = v;
    }
    __syncthreads();
    for (int t = lid; t < 38 * 38; t += NT) {
      int r = t / 38, c = t - r * 38;
      float v = 0.f;
      if ((ti - 3 + r) >= 1 && (ti - 3 + r) < n - 1 && (tj - 3 + c) >= 1 && (tj - 3 + c) < n - 1)
        v = C0F * (bufC[r * 41 + c + 1] + bufC[(r + 2) * 41 + c + 1] +
                   bufC[(r + 1) * 41 + c] + bufC[(r + 1) * 41 + c + 2] - bufB[(r + 1) * 41 + c + 1]);
      bufD[r * 39 + c] = v;
    }
    __syncthreads();
  }
  // Z -> bufA stride37 (36x36, org-2)
  for (int t = lid; t < 36 * 36; t += NT) {
    int r = t / 36, c = t - r * 36;
    float v = 0.f;
    if (INT || ((ti - 2 + r) >= 1 && (ti - 2 + r) < n - 1 && (tj - 2 + c) >= 1 && (tj - 2 + c) < n - 1))
      v = (bufD[r * 39 + c + 1] + bufD[(r + 2) * 39 + c + 1] +
           bufD[(r + 1) * 39 + c] + bufD[(r + 1) * 39 + c + 2]) * INV_DX2
          - bufD[(r + 1) * 39 + c + 1] * CENTER;
    bufA[r * 37 + c] = v;
  }
  __syncthreads();
  // Z2 -> bufC stride35 (34x34, org-1)
  for (int t = lid; t < 34 * 34; t += NT) {
    int r = t / 34, c = t - r * 34;
    float v = 0.f;
    if (INT || ((ti - 1 + r) >= 1 && (ti - 1 + r) < n - 1 && (tj - 1 + c) >= 1 && (tj - 1 + c) < n - 1))
      v = (bufA[r * 37 + c + 1] + bufA[(r + 2) * 37 + c + 1] +
           bufA[(r + 1) * 37 + c] + bufA[(r + 1) * 37 + c + 2]) * INV_DX2
          - bufA[(r + 1) * 37 + c + 1] * CENTER;
    bufC[r * 35 + c] = v;
  }
  __syncthreads();
  int tx = lid & 31, ty = lid >> 5;
  #pragma unroll
  for (int s = 0; s < 2; s++) {
    int yy = ty + 16 * s;
    int i = ti + yy, j = tj + tx;
    if (!INT && (i >= n || j >= n)) continue;
    size_t idx = base + (size_t)i * n + j;
    int pr = yy + 3, pc = tx + 3;
    psi_out[idx] = bufD[pr * 39 + pc];
    float qv = 0.f;
    if (INT || (i >= 1 && i < n - 1 && j >= 1 && j < n - 1)) {
      float z1v = bufA[(yy + 2) * 37 + tx + 2];
      int r2 = yy + 1, c2 = tx + 1;
      float z2v = bufC[r2 * 35 + c2];
      float z4 = (bufC[r2 * 35 + c2 - 1] + bufC[r2 * 35 + c2 + 1] +
                  bufC[(r2 - 1) * 35 + c2] + bufC[(r2 + 1) * 35 + c2]) * INV_DX2
                 - z2v * CENTER;
      float Amm = bufD[(pr - 1) * 39 + pc - 1], Am0 = bufD[(pr - 1) * 39 + pc],
            Amp = bufD[(pr - 1) * 39 + pc + 1];
      float A0m = bufD[pr * 39 + pc - 1], A0p = bufD[pr * 39 + pc + 1];
      float Apm = bufD[(pr + 1) * 39 + pc - 1], Ap0 = bufD[(pr + 1) * 39 + pc],
            App = bufD[(pr + 1) * 39 + pc + 1];
      int qr = yy + 4, qc = tx + 4;
      float J = (A0m - Am0) * bufB[(qr - 1) * 41 + qc - 1]
              + (Amm + A0m - Amp - A0p) * bufB[(qr - 1) * 41 + qc]
              + (Am0 - A0p) * bufB[(qr - 1) * 41 + qc + 1]
              + (Apm + Ap0 - Amm - Am0) * bufB[qr * 41 + qc - 1]
              + (Am0 + Amp - Ap0 - App) * bufB[qr * 41 + qc + 1]
              + (Ap0 - A0m) * bufB[(qr + 1) * 41 + qc - 1]
              + (A0p + App - A0m - Apm) * bufB[(qr + 1) * 41 + qc]
              + (A0p - Ap0) * bufB[(qr + 1) * 41 + qc + 1];
      J *= INV12S;
      float ct = CT[(size_t)i * n + j];
      qv = -J - 1e-6f * z1v + 1e-8f * z2v - 2e-11f * z4 + ct - 256.0f * (A0p - A0m);
    }
    qf_out[idx] = qv;
  }
}

__global__ __launch_bounds__(NT) void mega_k(
    const float* __restrict__ psi, const float* __restrict__ Qg,
    const float* __restrict__ q1g, const float* __restrict__ CT,
    float* __restrict__ psi_out, float* __restrict__ qf_out) {
  __shared__ float bufA[42 * 43];
  __shared__ float bufB[40 * 41];
  __shared__ float bufC[40 * 41];
  __shared__ float bufD[38 * 39];
  int bx = blockIdx.x, by = blockIdx.y;
  int ti = by * 32, tj = bx * 32;
  int c0i = 16 * by - 3, c0j = 16 * bx - 3;
  size_t base = (size_t)blockIdx.z * (N0 * N0);
  const float* q1 = q1g + (size_t)blockIdx.z * (N1 * N1);
  int lid = threadIdx.y * 32 + threadIdx.x;
  bool inter = (bx >= 1 && bx <= 14 && by >= 1 && by <= 14);
  if (inter)
    mega_body<true>(psi + base, Qg + base, q1, CT, psi_out, qf_out,
                    ti, tj, c0i, c0j, base, lid, bufA, bufB, bufC, bufD);
  else
    mega_body<false>(psi + base, Qg + base, q1, CT, psi_out, qf_out,
                     ti, tj, c0i, c0j, base, lid, bufA, bufB, bufC, bufD);
}

extern "C" void kernel_launch(void* const* d_in, const int* in_sizes, int n_in,
                              void* d_out, int out_size, void* d_ws, size_t ws_size,
                              hipStream_t stream) {
  const float* PSIG = (const float*)d_in[1];
  const float* Q    = (const float*)d_in[2];
  const float* CT   = (const float*)d_in[3];

  float* ws = (float*)d_ws;
  size_t f0 = (size_t)NB * N0 * N0;
  size_t f1 = (size_t)NB * N1 * N1;
  float* pA  = ws;
  float* pB  = pA + f0;
  float* q1a = pB + f0;
  float* q1b = q1a + f1;

  dim3 blk(32, 16, 1), grd(17, 17, NB);

  drelaxR_k<<<grd, blk, 0, stream>>>(PSIG, Q, pA, q1a);      // cycle-1 down
  vleg_k<<<grd, blk, 0, stream>>>(pA, Q, q1a, pB, q1b);      // c1 up + c2 down
  float* psi_out = (float*)d_out;
  float* qf_out  = psi_out + f0;
  mega_k<<<grd, blk, 0, stream>>>(pB, Q, q1b, CT, psi_out, qf_out);  // c2 up + flux
}